// Round 9
// baseline (1222.513 us; speedup 1.0000x reference)
//
#include <hip/hip_runtime.h>
#include <math.h>

// ---------------- constants ----------------
constexpr int L      = 2048;
constexpr int NH     = 16;
constexpr int DINNER = 1024;
constexpr int MNH    = 32;
constexpr int CONVCH = 1152;
constexpr int INDIM  = 2208;
constexpr int CHUNK  = 64;
constexpr int NCH    = 32;

using bf16x8 = __attribute__((ext_vector_type(8))) short;
using f32x4  = __attribute__((ext_vector_type(4))) float;

__device__ __forceinline__ f32x4 splat4(float x) { return (f32x4){x, x, x, x}; }

__device__ __forceinline__ unsigned short f2bf(float f) {
  unsigned u = __float_as_uint(f);
  return (unsigned short)((u + 0x7fffu + ((u >> 16) & 1u)) >> 16);
}
__device__ __forceinline__ float bf2f(unsigned short h) {
  return __uint_as_float((unsigned)h << 16);
}

// ---------------- fp32 GEMM v4: 128x256 block, 8x16 micro-tile ----------------
// 6 ds_read_b128 per kk for 128 FMAs (vs 4/64 in v3) -> LDS pipe no longer caps
// VALU at ~50%. Col chunks tx*4+j*64 keep B-reads 2-way bank-free. grid.z =
// split-K (atomicAdd; C pre-zeroed). M%128==0, K%(16*S)==0 assumed.
__global__ __launch_bounds__(256) void gemm_f32_v4(
    const float* __restrict__ A, const float* __restrict__ W,
    float* __restrict__ C, int M, int N, int K) {
  __shared__ float As[16][132];
  __shared__ float Ws[16][260];
  int tid = threadIdx.x;
  int bm = blockIdx.y * 128, bn = blockIdx.x * 256;
  int kper = K / gridDim.z;
  int kb = blockIdx.z * kper, ke = kb + kper;
  int tx = tid & 15, ty = tid >> 4;
  // loaders: A = 128 rows x 16k via 256 thr x 8 floats; W = 256 rows x 16k x 16 floats
  int ar = tid & 127;
  int ak = (tid >> 7) * 8;
  const float* arow = A + (size_t)(bm + ar) * K + ak;
  bool wok = (bn + tid < N);
  const float* wrow = W + (size_t)(bn + tid) * K;
  float4 a0, a1, w0, w1, w2, w3;
  auto gload = [&](int k0) {
    a0 = *(const float4*)(arow + k0);
    a1 = *(const float4*)(arow + k0 + 4);
    w0 = make_float4(0.f, 0.f, 0.f, 0.f); w1 = w0; w2 = w0; w3 = w0;
    if (wok) {
      w0 = *(const float4*)(wrow + k0);     w1 = *(const float4*)(wrow + k0 + 4);
      w2 = *(const float4*)(wrow + k0 + 8); w3 = *(const float4*)(wrow + k0 + 12);
    }
  };
  f32x4 acc[8][4] = {};
  gload(kb);
  for (int k0 = kb; k0 < ke; k0 += 16) {
    __syncthreads();
    As[ak+0][ar]=a0.x; As[ak+1][ar]=a0.y; As[ak+2][ar]=a0.z; As[ak+3][ar]=a0.w;
    As[ak+4][ar]=a1.x; As[ak+5][ar]=a1.y; As[ak+6][ar]=a1.z; As[ak+7][ar]=a1.w;
    Ws[ 0][tid]=w0.x; Ws[ 1][tid]=w0.y; Ws[ 2][tid]=w0.z; Ws[ 3][tid]=w0.w;
    Ws[ 4][tid]=w1.x; Ws[ 5][tid]=w1.y; Ws[ 6][tid]=w1.z; Ws[ 7][tid]=w1.w;
    Ws[ 8][tid]=w2.x; Ws[ 9][tid]=w2.y; Ws[10][tid]=w2.z; Ws[11][tid]=w2.w;
    Ws[12][tid]=w3.x; Ws[13][tid]=w3.y; Ws[14][tid]=w3.z; Ws[15][tid]=w3.w;
    __syncthreads();
    if (k0 + 16 < ke) gload(k0 + 16);  // prefetch overlaps compute
#pragma unroll
    for (int kk = 0; kk < 16; ++kk) {
      f32x4 al = *(const f32x4*)&As[kk][ty * 8];
      f32x4 ah = *(const f32x4*)&As[kk][ty * 8 + 4];
      f32x4 b0 = *(const f32x4*)&Ws[kk][tx * 4];
      f32x4 b1 = *(const f32x4*)&Ws[kk][64 + tx * 4];
      f32x4 b2 = *(const f32x4*)&Ws[kk][128 + tx * 4];
      f32x4 b3 = *(const f32x4*)&Ws[kk][192 + tx * 4];
#pragma unroll
      for (int i = 0; i < 4; ++i) {
        f32x4 sl = splat4(al[i]), sh = splat4(ah[i]);
        acc[i][0] += sl * b0; acc[i][1] += sl * b1;
        acc[i][2] += sl * b2; acc[i][3] += sl * b3;
        acc[i+4][0] += sh * b0; acc[i+4][1] += sh * b1;
        acc[i+4][2] += sh * b2; acc[i+4][3] += sh * b3;
      }
    }
  }
  bool single = (gridDim.z == 1);
#pragma unroll
  for (int i = 0; i < 8; ++i) {
    int row = bm + ty * 8 + i;
    float* crow = C + (size_t)row * N;
#pragma unroll
    for (int j = 0; j < 4; ++j) {
      int c = bn + j * 64 + tx * 4;
      if (c < N) {
        if (single) *(f32x4*)(crow + c) = acc[i][j];
        else {
          atomicAdd(crow + c + 0, acc[i][j][0]); atomicAdd(crow + c + 1, acc[i][j][1]);
          atomicAdd(crow + c + 2, acc[i][j][2]); atomicAdd(crow + c + 3, acc[i][j][3]);
        }
      }
    }
  }
}

// ---------------- fp32 GEMM v3 (skinny shapes): 128x128, 8x8 ----------------
__global__ __launch_bounds__(256) void gemm_f32_v3(
    const float* __restrict__ A, const float* __restrict__ W,
    float* __restrict__ C, int M, int N, int K) {
  __shared__ float As[16][132];
  __shared__ float Ws[16][132];
  int tid = threadIdx.x;
  int bm = blockIdx.y * 128, bn = blockIdx.x * 128;
  int kper = K / gridDim.z;
  int kb = blockIdx.z * kper, ke = kb + kper;
  int lr = tid >> 1;
  int lh = (tid & 1) * 8;
  int tx = tid & 15, ty = tid >> 4;
  bool wok = (bn + lr < N);
  const float* arow = A + (size_t)(bm + lr) * K + lh;
  const float* wrow = W + (size_t)(bn + lr) * K + lh;
  float4 a0, a1, w0, w1;
  auto gload = [&](int k0) {
    a0 = *(const float4*)(arow + k0);
    a1 = *(const float4*)(arow + k0 + 4);
    w0 = make_float4(0.f, 0.f, 0.f, 0.f); w1 = w0;
    if (wok) {
      w0 = *(const float4*)(wrow + k0);
      w1 = *(const float4*)(wrow + k0 + 4);
    }
  };
  f32x4 acc0[8] = {}, acc1[8] = {};
  gload(kb);
  for (int k0 = kb; k0 < ke; k0 += 16) {
    __syncthreads();
    As[lh+0][lr]=a0.x; As[lh+1][lr]=a0.y; As[lh+2][lr]=a0.z; As[lh+3][lr]=a0.w;
    As[lh+4][lr]=a1.x; As[lh+5][lr]=a1.y; As[lh+6][lr]=a1.z; As[lh+7][lr]=a1.w;
    Ws[lh+0][lr]=w0.x; Ws[lh+1][lr]=w0.y; Ws[lh+2][lr]=w0.z; Ws[lh+3][lr]=w0.w;
    Ws[lh+4][lr]=w1.x; Ws[lh+5][lr]=w1.y; Ws[lh+6][lr]=w1.z; Ws[lh+7][lr]=w1.w;
    __syncthreads();
    if (k0 + 16 < ke) gload(k0 + 16);
#pragma unroll
    for (int kk = 0; kk < 16; ++kk) {
      f32x4 b0 = *(const f32x4*)&Ws[kk][tx * 4];
      f32x4 b1 = *(const f32x4*)&Ws[kk][64 + tx * 4];
      f32x4 al = *(const f32x4*)&As[kk][ty * 8];
      f32x4 ah = *(const f32x4*)&As[kk][ty * 8 + 4];
#pragma unroll
      for (int i = 0; i < 4; ++i) {
        acc0[i]     += splat4(al[i]) * b0;
        acc1[i]     += splat4(al[i]) * b1;
        acc0[i + 4] += splat4(ah[i]) * b0;
        acc1[i + 4] += splat4(ah[i]) * b1;
      }
    }
  }
  bool single = (gridDim.z == 1);
#pragma unroll
  for (int i = 0; i < 8; ++i) {
    int row = bm + ty * 8 + i;
    float* crow = C + (size_t)row * N;
    int c0 = bn + tx * 4, c1 = bn + 64 + tx * 4;
    if (c0 + 3 < N) {
      if (single) *(f32x4*)(crow + c0) = acc0[i];
      else {
        atomicAdd(crow + c0 + 0, acc0[i][0]); atomicAdd(crow + c0 + 1, acc0[i][1]);
        atomicAdd(crow + c0 + 2, acc0[i][2]); atomicAdd(crow + c0 + 3, acc0[i][3]);
      }
    }
    if (c1 + 3 < N) {
      if (single) *(f32x4*)(crow + c1) = acc1[i];
      else {
        atomicAdd(crow + c1 + 0, acc1[i][0]); atomicAdd(crow + c1 + 1, acc1[i][1]);
        atomicAdd(crow + c1 + 2, acc1[i][2]); atomicAdd(crow + c1 + 3, acc1[i][3]);
      }
    }
  }
}

// ---------------- bf16 MFMA GEMM (value path) ----------------
__global__ __launch_bounds__(256) void gemm_bf16_kernel(
    const unsigned short* __restrict__ A, const unsigned short* __restrict__ W,
    float* __restrict__ C, int M, int N, int K, int lda, int ldb, int ldc) {
  __shared__ unsigned short As[128 * 64];
  __shared__ unsigned short Ws[128 * 64];
  int tid = threadIdx.x;
  int bm = blockIdx.y * 128, bn = blockIdx.x * 128;
  int kper = K / gridDim.z;
  int k_begin = blockIdx.z * kper;
  int k_end = k_begin + kper;
  int wv = tid >> 6, lane = tid & 63;
  int wrow = (wv >> 1) * 64, wcol = (wv & 1) * 64;
  int lrow = lane & 15, quad = lane >> 4;

  f32x4 acc[4][4] = {};

  for (int k0 = k_begin; k0 < k_end; k0 += 64) {
    __syncthreads();
#pragma unroll
    for (int it = 0; it < 4; ++it) {
      int s = it * 256 + tid;
      int r = s >> 3;
      int q = (s & 7) ^ (r & 7);
      const unsigned short* ga = A + (size_t)(bm + r) * lda + k0 + q * 8;
      const unsigned short* gw = W + (size_t)(bn + r) * ldb + k0 + q * 8;
      __builtin_amdgcn_global_load_lds((const __attribute__((address_space(1))) void*)ga,
                                       (__attribute__((address_space(3))) void*)&As[s * 8], 16, 0, 0);
      __builtin_amdgcn_global_load_lds((const __attribute__((address_space(1))) void*)gw,
                                       (__attribute__((address_space(3))) void*)&Ws[s * 8], 16, 0, 0);
    }
    __syncthreads();
#pragma unroll
    for (int ks = 0; ks < 2; ++ks) {
      bf16x8 af[4], wf[4];
#pragma unroll
      for (int i = 0; i < 4; ++i) {
        int ra = wrow + i * 16 + lrow;
        int qa = (ks * 4 + quad) ^ (ra & 7);
        af[i] = *(const bf16x8*)&As[(ra * 8 + qa) * 8];
        int rw = wcol + i * 16 + lrow;
        int qw = (ks * 4 + quad) ^ (rw & 7);
        wf[i] = *(const bf16x8*)&Ws[(rw * 8 + qw) * 8];
      }
#pragma unroll
      for (int i = 0; i < 4; ++i)
#pragma unroll
        for (int j = 0; j < 4; ++j)
          acc[i][j] = __builtin_amdgcn_mfma_f32_16x16x32_bf16(af[i], wf[j], acc[i][j], 0, 0, 0);
    }
  }
  bool single = (gridDim.z == 1);
#pragma unroll
  for (int i = 0; i < 4; ++i)
#pragma unroll
    for (int j = 0; j < 4; ++j)
#pragma unroll
      for (int r = 0; r < 4; ++r) {
        int row = bm + wrow + i * 16 + quad * 4 + r;
        int col = bn + wcol + j * 16 + lrow;
        float v = acc[i][j][r];
        if (single) C[(size_t)row * ldc + col] = v;
        else atomicAdd(&C[(size_t)row * ldc + col], v);
      }
}

// ---------------- conversions (split-bf16 aug) ----------------
__global__ __launch_bounds__(256) void conv_augA_kernel(
    const float* __restrict__ src, unsigned short* __restrict__ dst,
    int total, int K, int sld) {
  int i = blockIdx.x * 256 + threadIdx.x;
  if (i >= total) return;
  int m = i / K, k = i - m * K;
  float f = src[(size_t)m * sld + k];
  unsigned short hi = f2bf(f);
  unsigned short lo = f2bf(f - bf2f(hi));
  size_t o = ((size_t)m * K + k) * 3;
  dst[o] = hi; dst[o + 1] = lo; dst[o + 2] = hi;
}
__global__ __launch_bounds__(256) void conv_augW_kernel(
    const float* __restrict__ src, unsigned short* __restrict__ dst,
    int rows, int total, int K, int sld) {
  int i = blockIdx.x * 256 + threadIdx.x;
  if (i >= total) return;
  int n = i / K, k = i - n * K;
  unsigned short hi = 0, lo = 0;
  if (n < rows) {
    float f = src[(size_t)n * sld + k];
    hi = f2bf(f);
    lo = f2bf(f - bf2f(hi));
  }
  size_t o = ((size_t)n * K + k) * 3;
  dst[o] = hi; dst[o + 1] = hi; dst[o + 2] = lo;
}

// ---------------- conv1d(4-tap, causal) + SiLU ----------------
__global__ __launch_bounds__(256) void conv_silu_kernel(
    const float* __restrict__ zxbcdt, const float* __restrict__ conv_w,
    const float* __restrict__ conv_b, float* __restrict__ xBC) {
  int idx = blockIdx.x * 256 + threadIdx.x;
  if (idx >= L * CONVCH) return;
  int l = idx / CONVCH, c = idx - l * CONVCH;
  float acc = conv_b[c];
#pragma unroll
  for (int k = 0; k < 4; ++k) {
    int ls = l - 3 + k;
    if (ls >= 0) acc += zxbcdt[(size_t)ls * INDIM + DINNER + c] * conv_w[c * 4 + k];
  }
  xBC[idx] = acc / (1.f + expf(-acc));
}

// ---------------- dt / logdA ----------------
__global__ __launch_bounds__(256) void dt_kernel(
    const float* __restrict__ zxbcdt, const float* __restrict__ dt_bias,
    const float* __restrict__ A_log, float* __restrict__ dt, float* __restrict__ logdA) {
  int idx = blockIdx.x * 256 + threadIdx.x;
  int l = idx >> 5, h = idx & 31;
  float xv = zxbcdt[(size_t)l * INDIM + (INDIM - MNH) + h] + dt_bias[h];
  float sp = fmaxf(xv, 0.f) + log1pf(expf(-fabsf(xv)));
  dt[idx] = sp;
  logdA[idx] = sp * -expf(A_log[h]);
}

// ---------------- lcd: per-(chunk,head) inclusive cumsum of logdA ----------------
__global__ __launch_bounds__(256) void lcd_kernel(
    const float* __restrict__ logdA, float* __restrict__ lcd) {
  int i = blockIdx.x * 256 + threadIdx.x;
  if (i >= NCH * MNH) return;
  int c = i >> 5, h = i & 31;
  float s = 0.f;
  for (int t = 0; t < CHUNK; ++t) {
    s += logdA[(c * CHUNK + t) * MNH + h];
    lcd[(size_t)i * CHUNK + t] = s;
  }
}

// ---------------- G[c][t][s] = C_t . B_s ----------------
__global__ __launch_bounds__(256) void chunk_G_kernel(
    const float* __restrict__ xBC, float* __restrict__ G) {
  int c = blockIdx.x, tid = threadIdx.x;
  __shared__ float BsT[64][68];
  __shared__ float Cs[64][65];
  int t = tid >> 2, q = tid & 3;
  const float* row = xBC + (size_t)(c * 64 + t) * CONVCH + DINNER;
#pragma unroll
  for (int j = 0; j < 16; j += 4) {
    float4 b = *(const float4*)(row + q * 16 + j);
    BsT[q * 16 + j + 0][t] = b.x; BsT[q * 16 + j + 1][t] = b.y;
    BsT[q * 16 + j + 2][t] = b.z; BsT[q * 16 + j + 3][t] = b.w;
    float4 cv = *(const float4*)(row + 64 + q * 16 + j);
    Cs[t][q * 16 + j + 0] = cv.x; Cs[t][q * 16 + j + 1] = cv.y;
    Cs[t][q * 16 + j + 2] = cv.z; Cs[t][q * 16 + j + 3] = cv.w;
  }
  __syncthreads();
  int s0 = q * 16;
  f32x4 g0 = {}, g1 = {}, g2 = {}, g3 = {};
  for (int n = 0; n < 64; ++n) {
    f32x4 cv = splat4(Cs[t][n]);
    g0 += cv * *(const f32x4*)&BsT[n][s0];
    g1 += cv * *(const f32x4*)&BsT[n][s0 + 4];
    g2 += cv * *(const f32x4*)&BsT[n][s0 + 8];
    g3 += cv * *(const f32x4*)&BsT[n][s0 + 12];
  }
  float* gp = G + ((size_t)c * 64 + t) * 64 + s0;
  *(f32x4*)gp = g0; *(f32x4*)(gp + 4) = g1; *(f32x4*)(gp + 8) = g2; *(f32x4*)(gp + 12) = g3;
}

// ---------------- scan pass A ----------------
__global__ __launch_bounds__(256) void scan_local_kernel(
    const float* __restrict__ xBC, const float* __restrict__ dt,
    const float* __restrict__ lcd, float* __restrict__ hstate) {
  int c = blockIdx.x >> 5, h = blockIdx.x & 31;
  int tid = threadIdx.x;
  __shared__ float Bs[64][68];
  __shared__ float xss[64][36];
  __shared__ float w2s[64];
  int t0 = c * CHUNK;
  int t = tid >> 2, q = tid & 3;
  const float* row = xBC + (size_t)(t0 + t) * CONVCH;
#pragma unroll
  for (int j = 0; j < 16; j += 4)
    *(float4*)&Bs[t][q * 16 + j] = *(const float4*)(row + DINNER + q * 16 + j);
  if (q < 2) {
#pragma unroll
    for (int j = 0; j < 16; j += 4)
      *(float4*)&xss[t][q * 16 + j] = *(const float4*)(row + h * 32 + q * 16 + j);
  }
  if (tid < 64) {
    const float* lc = lcd + ((size_t)c * 32 + h) * CHUNK;
    w2s[tid] = expf(lc[63] - lc[tid]) * dt[(t0 + tid) * MNH + h];
  }
  __syncthreads();
  int n = tid >> 2, pg = (tid & 3) * 8;
  f32x4 h0 = {}, h1 = {};
  for (int s = 0; s < 64; ++s) {
    f32x4 wb = splat4(w2s[s] * Bs[s][n]);
    h0 += wb * *(const f32x4*)&xss[s][pg];
    h1 += wb * *(const f32x4*)&xss[s][pg + 4];
  }
  float* hp = hstate + ((size_t)c * 32 + h) * 2048 + n * 32 + pg;
  *(f32x4*)hp = h0; *(f32x4*)(hp + 4) = h1;
}

// ---------------- scan pass B ----------------
__global__ __launch_bounds__(256) void scan_combine_kernel(
    float* __restrict__ hstate, const float* __restrict__ lcd) {
  int i = blockIdx.x * 256 + threadIdx.x;
  int h = i >> 11;
  float H = 0.f;
  for (int c = 0; c < NCH; ++c) {
    float hl = hstate[(size_t)c * 65536 + i];
    hstate[(size_t)c * 65536 + i] = H;
    float P = expf(lcd[((size_t)c * 32 + h) * CHUNK + CHUNK - 1]);
    H = H * P + hl;
  }
}

// ---------------- scan pass C ----------------
__global__ __launch_bounds__(256) void scan_y_kernel(
    const float* __restrict__ xBC, const float* __restrict__ G,
    const float* __restrict__ dt, const float* __restrict__ lcd,
    const float* __restrict__ hstate, float* __restrict__ y) {
  int c = blockIdx.x >> 5, h = blockIdx.x & 31;
  int tid = threadIdx.x;
  __shared__ float Ms[64][65];
  __shared__ float Cs[64][65];
  __shared__ float xss[64][36];
  __shared__ float Hss[64][36];
  __shared__ float lcds[64], dts[64];
  int t0 = c * CHUNK;
  int t = tid >> 2, q = tid & 3;
  const float* row = xBC + (size_t)(t0 + t) * CONVCH;
#pragma unroll
  for (int j = 0; j < 16; j += 4) {
    float4 cv = *(const float4*)(row + DINNER + 64 + q * 16 + j);
    Cs[t][q * 16 + j + 0] = cv.x; Cs[t][q * 16 + j + 1] = cv.y;
    Cs[t][q * 16 + j + 2] = cv.z; Cs[t][q * 16 + j + 3] = cv.w;
  }
  if (q < 2) {
#pragma unroll
    for (int j = 0; j < 16; j += 4)
      *(float4*)&xss[t][q * 16 + j] = *(const float4*)(row + h * 32 + q * 16 + j);
  }
  {
    const float* gp = G + ((size_t)c * 64 + t) * 64 + q * 16;
#pragma unroll
    for (int j = 0; j < 16; j += 4) {
      float4 g = *(const float4*)(gp + j);
      Ms[t][q * 16 + j + 0] = g.x; Ms[t][q * 16 + j + 1] = g.y;
      Ms[t][q * 16 + j + 2] = g.z; Ms[t][q * 16 + j + 3] = g.w;
    }
  }
  {
    const float* hp = hstate + ((size_t)c * 32 + h) * 2048 + tid * 8;
    int n = tid >> 2, p0 = (tid & 3) * 8;
    *(float4*)&Hss[n][p0]     = *(const float4*)hp;
    *(float4*)&Hss[n][p0 + 4] = *(const float4*)(hp + 4);
  }
  if (tid < 64) {
    lcds[tid] = lcd[((size_t)c * 32 + h) * CHUNK + tid];
    dts[tid]  = dt[(t0 + tid) * MNH + h];
  }
  __syncthreads();
  {
    int s0 = q * 16;
#pragma unroll
    for (int j = 0; j < 16; ++j) {
      int s = s0 + j;
      float m = (s <= t) ? expf(lcds[t] - lcds[s]) * dts[s] * Ms[t][s] : 0.f;
      Ms[t][s] = m;
    }
  }
  __syncthreads();
  int pg = q * 8;
  f32x4 y0 = {}, y1 = {}, a0 = {}, a1 = {};
  for (int s = 0; s < 64; ++s) {
    f32x4 m = splat4(Ms[t][s]);
    y0 += m * *(const f32x4*)&xss[s][pg];
    y1 += m * *(const f32x4*)&xss[s][pg + 4];
  }
  for (int n = 0; n < 64; ++n) {
    f32x4 cn = splat4(Cs[t][n]);
    a0 += cn * *(const f32x4*)&Hss[n][pg];
    a1 += cn * *(const f32x4*)&Hss[n][pg + 4];
  }
  f32x4 cd = splat4(expf(lcds[t]));
  y0 += cd * a0; y1 += cd * a1;
  float* yp = y + (size_t)(t0 + t) * DINNER + h * 32 + pg;
  *(f32x4*)yp = y0; *(f32x4*)(yp + 4) = y1;
}

// ---------------- gate + RMSNorm ----------------
__global__ __launch_bounds__(256) void gatenorm_kernel(
    const float* __restrict__ y_ssm, const float* __restrict__ xBC,
    const float* __restrict__ zxbcdt, const float* __restrict__ Dv,
    const float* __restrict__ norm_w, float* __restrict__ out) {
  int l = blockIdx.x, tid = threadIdx.x;
  float vals[4];
  float ss = 0.f;
#pragma unroll
  for (int i = 0; i < 4; ++i) {
    int d = tid + i * 256;
    int h = d >> 5;
    float v = y_ssm[(size_t)l * DINNER + d] + Dv[h] * xBC[(size_t)l * CONVCH + d];
    float z = zxbcdt[(size_t)l * INDIM + d];
    v *= z / (1.f + expf(-z));
    vals[i] = v;
    ss += v * v;
  }
#pragma unroll
  for (int off = 32; off > 0; off >>= 1) ss += __shfl_xor(ss, off);
  __shared__ float sred[4];
  if ((tid & 63) == 0) sred[tid >> 6] = ss;
  __syncthreads();
  float tot = sred[0] + sred[1] + sred[2] + sred[3];
  float scale = rsqrtf(tot * (1.f / 1024.f) + 1e-5f);
#pragma unroll
  for (int i = 0; i < 4; ++i) {
    int d = tid + i * 256;
    out[(size_t)l * DINNER + d] = vals[i] * scale * norm_w[d];
  }
}

// ---------------- per-row top-64 radix select ----------------
__global__ __launch_bounds__(256) void topk_kernel(
    const float* __restrict__ scores, int* __restrict__ out_idx) {
  int l = blockIdx.x, tid = threadIdx.x;
  if (l < 64) {
    if (tid < 64) out_idx[l * 64 + tid] = tid;
    return;
  }
  int n = l + 1;
  const float* row = scores + (size_t)l * L;
  __shared__ int hist[256];
  __shared__ unsigned sel_prefix;
  __shared__ int sel_remaining;
  __shared__ int cnt_g, cnt_e;
  __shared__ int eq_list[128];
  if (tid == 0) { cnt_g = 0; cnt_e = 0; }
  unsigned prefix = 0;
  int remaining = 64;
  for (int pass = 0; pass < 4; ++pass) {
    int shift = 24 - 8 * pass;
    unsigned himask = (pass == 0) ? 0u : (0xFFFFFFFFu << (shift + 8));
    hist[tid] = 0;
    __syncthreads();
    for (int j = tid; j < n; j += 256) {
      unsigned u = __float_as_uint(row[j]);
      unsigned key = (u & 0x80000000u) ? ~u : (u | 0x80000000u);
      if (((key ^ prefix) & himask) == 0)
        atomicAdd(&hist[(key >> shift) & 255], 1);
    }
    __syncthreads();
    if (tid == 0) {
      int cum = 0, b = 255;
      for (; b >= 0; --b) {
        cum += hist[b];
        if (cum >= remaining) break;
      }
      sel_prefix = prefix | ((unsigned)b << shift);
      sel_remaining = remaining - (cum - hist[b]);
    }
    __syncthreads();
    prefix = sel_prefix;
    remaining = sel_remaining;
    __syncthreads();
  }
  unsigned T = prefix;
  for (int j = tid; j < n; j += 256) {
    unsigned u = __float_as_uint(row[j]);
    unsigned key = (u & 0x80000000u) ? ~u : (u | 0x80000000u);
    if (key > T) {
      int p = atomicAdd(&cnt_g, 1);
      out_idx[l * 64 + p] = j;
    } else if (key == T) {
      int p = atomicAdd(&cnt_e, 1);
      if (p < 128) eq_list[p] = j;
    }
  }
  __syncthreads();
  if (tid == 0) {
    int G = cnt_g;
    int E = remaining;
    int m = cnt_e < 128 ? cnt_e : 128;
    for (int e = 0; e < E; ++e) {
      int best = 0, bj = 0x7fffffff;
      for (int i = 0; i < m; ++i)
        if (eq_list[i] < bj) { bj = eq_list[i]; best = i; }
      out_idx[l * 64 + G + e] = bj;
      eq_list[best] = 0x7fffffff;
    }
  }
}

// ---------------- RoPE + pack q_final/k_final ----------------
__global__ __launch_bounds__(128) void rope_pack_kernel(
    const float* __restrict__ q_content, const float* __restrict__ q_rope_lin,
    const float* __restrict__ kv, const float* __restrict__ k_rope_lin,
    float* __restrict__ q_final, float* __restrict__ k_final) {
  int l = blockIdx.x, tid = threadIdx.x;
  __shared__ float s_s[16], s_c[16];
  if (tid < 16) {
    float inv = powf(10000.f, -(float)tid / 16.f);
    float ang = (float)l * inv;
    s_s[tid] = sinf(ang);
    s_c[tid] = cosf(ang);
  }
  __syncthreads();
  for (int e = tid; e < NH * 96; e += 128) {
    int hh = e / 96, d = e - hh * 96;
    float qv, kvv;
    if (d < 64) {
      qv  = q_content[(size_t)l * 1024 + hh * 64 + d];
      kvv = kv[(size_t)l * 2048 + hh * 64 + d];
    } else {
      int r = d - 64;
      if (r < 16) {
        float q1 = q_rope_lin[(size_t)l * 512 + hh * 32 + r];
        float q2 = q_rope_lin[(size_t)l * 512 + hh * 32 + 16 + r];
        qv = q1 * s_c[r] - q2 * s_s[r];
        float k1 = k_rope_lin[(size_t)l * 128 + r];
        float k2 = k_rope_lin[(size_t)l * 128 + 16 + r];
        kvv = k1 * s_c[r] - k2 * s_s[r];
      } else {
        int rr = r - 16;
        float q1 = q_rope_lin[(size_t)l * 512 + hh * 32 + rr];
        float q2 = q_rope_lin[(size_t)l * 512 + hh * 32 + 16 + rr];
        qv = q1 * s_s[rr] + q2 * s_c[rr];
        float k1 = k_rope_lin[(size_t)l * 128 + rr];
        float k2 = k_rope_lin[(size_t)l * 128 + 16 + rr];
        kvv = k1 * s_s[rr] + k2 * s_c[rr];
      }
    }
    q_final[(size_t)l * 1536 + e] = qv;
    k_final[(size_t)l * 1536 + e] = kvv;
  }
}

// ---------------- sparse attention ----------------
__global__ __launch_bounds__(256) void attn_kernel(
    const float* __restrict__ q_final, const float* __restrict__ k_final,
    const float* __restrict__ kv, const int* __restrict__ idx,
    unsigned short* __restrict__ attn_aug) {
  int w = blockIdx.x * 4 + (threadIdx.x >> 6);
  int lane = threadIdx.x & 63;
  int l = w >> 4, h = w & 15;
  int ik = idx[l * 64 + lane];
  const float4* qp = (const float4*)(q_final + (size_t)l * 1536 + h * 96);
  const float4* kp = (const float4*)(k_final + (size_t)ik * 1536 + h * 96);
  float dot = 0.f;
#pragma unroll
  for (int j = 0; j < 24; ++j) {
    float4 q4 = qp[j], k4 = kp[j];
    dot += q4.x * k4.x + q4.y * k4.y + q4.z * k4.z + q4.w * k4.w;
  }
  float logit = dot * 0.10206207261596575f;
  float m = logit;
#pragma unroll
  for (int off = 32; off > 0; off >>= 1) m = fmaxf(m, __shfl_xor(m, off));
  float e = expf(logit - m);
  float ssum = e;
#pragma unroll
  for (int off = 32; off > 0; off >>= 1) ssum += __shfl_xor(ssum, off);
  float wgt = e / ssum;
  float acc = 0.f;
  const float* vbase = kv + 1024 + h * 64 + lane;
  for (int k = 0; k < 64; ++k) {
    float wk = __shfl(wgt, k);
    int kk = __shfl(ik, k);
    acc += wk * vbase[(size_t)kk * 2048];
  }
  unsigned short hi = f2bf(acc);
  unsigned short lo = f2bf(acc - bf2f(hi));
  size_t o = ((size_t)l * 1024 + h * 64 + lane) * 3;
  attn_aug[o] = hi; attn_aug[o + 1] = lo; attn_aug[o + 2] = hi;
}

// ---------------- host ----------------
extern "C" void kernel_launch(void* const* d_in, const int* in_sizes, int n_in,
                              void* d_out, int out_size, void* d_ws, size_t ws_size,
                              hipStream_t stream) {
  const float* x          = (const float*)d_in[0];
  const float* idx_in_w   = (const float*)d_in[1];
  const float* idx_conv_w = (const float*)d_in[2];
  const float* idx_conv_b = (const float*)d_in[3];
  const float* idx_dt_b   = (const float*)d_in[4];
  const float* idx_A_log  = (const float*)d_in[5];
  const float* idx_D      = (const float*)d_in[6];
  const float* idx_norm_w = (const float*)d_in[7];
  const float* idx_out_w  = (const float*)d_in[8];
  const float* idx_q_w    = (const float*)d_in[9];
  const float* idx_k_w    = (const float*)d_in[10];
  const float* q_down_w   = (const float*)d_in[11];
  const float* q_up_w     = (const float*)d_in[12];
  const float* q_rope_w   = (const float*)d_in[13];
  const float* kv_down_w  = (const float*)d_in[14];
  const float* kv_up_w    = (const float*)d_in[15];
  const float* k_rope_w   = (const float*)d_in[16];
  const float* out_w      = (const float*)d_in[17];
  float* out = (float*)d_out;

  // ---- workspace arena ----
  float* p = (float*)d_ws;
  float* segA = p; p += 4521984;
  float* segB = p; p += 2359296;
  float* dtb = p; p += 65536;
  float* logdA = p; p += 65536;
  float* lcdb = p; p += 65536;
  int*   idxb = (int*)p; p += 131072;
  float* segD = p; p += 4194304;
  float* segE = p; p += 3145728;
  float* segG = p; p += 3145728;
  float* segH = p; p += 3145728;
  unsigned short* w_qdown_aug  = (unsigned short*)p; p += 196608;
  unsigned short* w_kvdown_aug = (unsigned short*)p; p += 196608;
  unsigned short* w_krope_aug  = (unsigned short*)p; p += 196608;
  unsigned short* w_qup_aug    = (unsigned short*)p; p += 196608;
  unsigned short* w_qrope_aug  = (unsigned short*)p; p += 98304;
  unsigned short* w_kvup_aug   = (unsigned short*)p; p += 393216;
  unsigned short* c_q_aug      = (unsigned short*)p; p += 393216;
  unsigned short* c_kv_aug     = (unsigned short*)p; p += 393216;
  float* Gbuf = p; p += 131072;

  float* zxbcdt   = segA;
  float* scores   = segA;
  float* q_cont   = segA;
  float* q_rope_l = segA + 2097152;
  unsigned short* w_outp_aug = (unsigned short*)segA;
  float* xBC      = segB;
  float* q_idx    = segB;
  float* k_idx    = segB + 131072;
  float* c_q      = segB + 262144;
  float* c_kv     = segB + 524288;
  float* k_rope_l = segB + 786432;
  float* y_ssm  = segD;
  float* hstate = segD + 2097152;
  float* kvb    = segD;
  unsigned short* x_aug    = (unsigned short*)segE;
  unsigned short* attn_aug = (unsigned short*)segE;
  float* y_norm  = segG;
  float* q_final = segG;
  float* x_mamba = segH;
  float* k_final = segH;

  dim3 blk(256);
  auto cdiv = [](int a, int b) { return (a + b - 1) / b; };
  auto gemmf4 = [&](const float* A, const float* W, float* C, int M, int N, int K, int S) {
    dim3 grid(cdiv(N, 256), M / 128, S);
    hipLaunchKernelGGL(gemm_f32_v4, grid, blk, 0, stream, A, W, C, M, N, K);
  };
  auto gemmf3 = [&](const float* A, const float* W, float* C, int M, int N, int K, int S) {
    dim3 grid(cdiv(N, 128), M / 128, S);
    hipLaunchKernelGGL(gemm_f32_v3, grid, blk, 0, stream, A, W, C, M, N, K);
  };
  auto gemmb = [&](const unsigned short* A, const unsigned short* W, float* C,
                   int M, int N, int K, int lda, int ldb, int ldc, int S) {
    dim3 grid(N / 128, M / 128, S);
    hipLaunchKernelGGL(gemm_bf16_kernel, grid, blk, 0, stream, A, W, C, M, N, K, lda, ldb, ldc);
  };
  auto caugA = [&](const float* s, unsigned short* d, int total, int K, int sld) {
    hipLaunchKernelGGL(conv_augA_kernel, dim3(cdiv(total, 256)), blk, 0, stream, s, d, total, K, sld);
  };
  auto caugW = [&](const float* s, unsigned short* d, int rows, int total, int K, int sld) {
    hipLaunchKernelGGL(conv_augW_kernel, dim3(cdiv(total, 256)), blk, 0, stream, s, d, rows, total, K, sld);
  };

  // ---- mamba branch + index path: FULL FP32 ----
  caugA(x, x_aug, 2048 * 1024, 1024, 1024);
  hipMemsetAsync(zxbcdt, 0, (size_t)L * INDIM * 4, stream);
  gemmf4(x, idx_in_w, zxbcdt, 2048, INDIM, 1024, 4);
  hipLaunchKernelGGL(conv_silu_kernel, dim3(cdiv(L * CONVCH, 256)), blk, 0, stream,
                     zxbcdt, idx_conv_w, idx_conv_b, xBC);
  hipLaunchKernelGGL(dt_kernel, dim3(L * MNH / 256), blk, 0, stream,
                     zxbcdt, idx_dt_b, idx_A_log, dtb, logdA);
  hipLaunchKernelGGL(lcd_kernel, dim3(4), blk, 0, stream, logdA, lcdb);
  hipLaunchKernelGGL(chunk_G_kernel, dim3(NCH), blk, 0, stream, xBC, Gbuf);
  hipLaunchKernelGGL(scan_local_kernel, dim3(NCH * MNH), blk, 0, stream,
                     xBC, dtb, lcdb, hstate);
  hipLaunchKernelGGL(scan_combine_kernel, dim3(256), blk, 0, stream, hstate, lcdb);
  hipLaunchKernelGGL(scan_y_kernel, dim3(NCH * MNH), blk, 0, stream,
                     xBC, Gbuf, dtb, lcdb, hstate, y_ssm);
  hipLaunchKernelGGL(gatenorm_kernel, dim3(L), blk, 0, stream,
                     y_ssm, xBC, zxbcdt, idx_D, idx_norm_w, y_norm);
  hipMemsetAsync(x_mamba, 0, 2097152 * 4, stream);
  gemmf4(y_norm, idx_out_w, x_mamba, 2048, 1024, 1024, 8);
  hipMemsetAsync(q_idx, 0, 131072 * 4, stream);
  hipMemsetAsync(k_idx, 0, 131072 * 4, stream);
  gemmf3(x_mamba, idx_q_w, q_idx, 2048, 64, 1024, 16);
  gemmf3(x, idx_k_w, k_idx, 2048, 64, 1024, 16);
  gemmf3(q_idx, k_idx, scores, 2048, 2048, 64, 1);
  hipLaunchKernelGGL(topk_kernel, dim3(L), blk, 0, stream, scores, idxb);

  // ---- attention value path: aug split-bf16 MFMA ----
  caugW(q_down_w, w_qdown_aug, 128, 128 * 1024, 1024, 1024);
  caugW(kv_down_w, w_kvdown_aug, 128, 128 * 1024, 1024, 1024);
  caugW(k_rope_w, w_krope_aug, 32, 128 * 1024, 1024, 1024);
  hipMemsetAsync(c_q, 0, 262144 * 4, stream);
  hipMemsetAsync(c_kv, 0, 262144 * 4, stream);
  hipMemsetAsync(k_rope_l, 0, 262144 * 4, stream);
  gemmb(x_aug, w_qdown_aug, c_q, 2048, 128, 3072, 3072, 3072, 128, 8);
  gemmb(x_aug, w_kvdown_aug, c_kv, 2048, 128, 3072, 3072, 3072, 128, 8);
  gemmb(x_aug, w_krope_aug, k_rope_l, 2048, 128, 3072, 3072, 3072, 128, 8);
  caugA(c_q, c_q_aug, 2048 * 128, 128, 128);
  caugA(c_kv, c_kv_aug, 2048 * 128, 128, 128);
  caugW(q_up_w, w_qup_aug, 1024, 1024 * 128, 128, 128);
  caugW(q_rope_w, w_qrope_aug, 512, 512 * 128, 128, 128);
  caugW(kv_up_w, w_kvup_aug, 2048, 2048 * 128, 128, 128);
  hipMemsetAsync(q_rope_l, 0, 1048576 * 4, stream);
  gemmb(c_q_aug, w_qup_aug, q_cont, 2048, 1024, 384, 384, 384, 1024, 1);
  gemmb(c_q_aug, w_qrope_aug, q_rope_l, 2048, 512, 384, 384, 384, 512, 2);
  gemmb(c_kv_aug, w_kvup_aug, kvb, 2048, 2048, 384, 384, 384, 2048, 1);
  hipLaunchKernelGGL(rope_pack_kernel, dim3(L), dim3(128), 0, stream,
                     q_cont, q_rope_l, kvb, k_rope_l, q_final, k_final);

  // ---- sparse attention + output projection ----
  caugW(out_w, w_outp_aug, 1024, 1024 * 1024, 1024, 1024);
  hipLaunchKernelGGL(attn_kernel, dim3(L * NH / 4), blk, 0, stream,
                     q_final, k_final, kvb, idxb, attn_aug);
  hipMemsetAsync(out, 0, (size_t)out_size * 4, stream);
  gemmb(attn_aug, w_outp_aug, out, 2048, 1024, 3072, 3072, 3072, 1024, 2);
}

// Round 10
// 1076.120 us; speedup vs baseline: 1.1360x; 1.1360x over previous
//
#include <hip/hip_runtime.h>
#include <math.h>

// ---------------- constants ----------------
constexpr int L      = 2048;
constexpr int NH     = 16;
constexpr int DINNER = 1024;
constexpr int MNH    = 32;
constexpr int CONVCH = 1152;
constexpr int INDIM  = 2208;
constexpr int CHUNK  = 64;
constexpr int NCH    = 32;

using bf16x8 = __attribute__((ext_vector_type(8))) short;
using f32x4  = __attribute__((ext_vector_type(4))) float;

__device__ __forceinline__ f32x4 splat4(float x) { return (f32x4){x, x, x, x}; }

__device__ __forceinline__ unsigned short f2bf(float f) {
  unsigned u = __float_as_uint(f);
  return (unsigned short)((u + 0x7fffu + ((u >> 16) & 1u)) >> 16);
}
__device__ __forceinline__ float bf2f(unsigned short h) {
  return __uint_as_float((unsigned)h << 16);
}

// ---------------- fp32 GEMM v4: 128x256 block, 8x16 micro-tile ----------------
// __launch_bounds__(256,1): 128-float accumulator + staging needs ~200 VGPRs;
// default heuristic capped at 100 and spilled (R9: WRITE_SIZE 283 MB, 333 us).
// 1 wave/EU allows full VGPR budget; R8 proved >1 block/CU doesn't help here.
__global__ __launch_bounds__(256, 1) void gemm_f32_v4(
    const float* __restrict__ A, const float* __restrict__ W,
    float* __restrict__ C, int M, int N, int K) {
  __shared__ float As[16][132];
  __shared__ float Ws[16][260];
  int tid = threadIdx.x;
  int bm = blockIdx.y * 128, bn = blockIdx.x * 256;
  int kper = K / gridDim.z;
  int kb = blockIdx.z * kper, ke = kb + kper;
  int tx = tid & 15, ty = tid >> 4;
  int ar = tid & 127;
  int ak = (tid >> 7) * 8;
  const float* arow = A + (size_t)(bm + ar) * K + ak;
  bool wok = (bn + tid < N);
  const float* wrow = W + (size_t)(bn + tid) * K;
  float4 a0, a1, w0, w1, w2, w3;
  auto gload = [&](int k0) {
    a0 = *(const float4*)(arow + k0);
    a1 = *(const float4*)(arow + k0 + 4);
    w0 = make_float4(0.f, 0.f, 0.f, 0.f); w1 = w0; w2 = w0; w3 = w0;
    if (wok) {
      w0 = *(const float4*)(wrow + k0);     w1 = *(const float4*)(wrow + k0 + 4);
      w2 = *(const float4*)(wrow + k0 + 8); w3 = *(const float4*)(wrow + k0 + 12);
    }
  };
  f32x4 acc[8][4] = {};
  gload(kb);
  for (int k0 = kb; k0 < ke; k0 += 16) {
    __syncthreads();
    As[ak+0][ar]=a0.x; As[ak+1][ar]=a0.y; As[ak+2][ar]=a0.z; As[ak+3][ar]=a0.w;
    As[ak+4][ar]=a1.x; As[ak+5][ar]=a1.y; As[ak+6][ar]=a1.z; As[ak+7][ar]=a1.w;
    Ws[ 0][tid]=w0.x; Ws[ 1][tid]=w0.y; Ws[ 2][tid]=w0.z; Ws[ 3][tid]=w0.w;
    Ws[ 4][tid]=w1.x; Ws[ 5][tid]=w1.y; Ws[ 6][tid]=w1.z; Ws[ 7][tid]=w1.w;
    Ws[ 8][tid]=w2.x; Ws[ 9][tid]=w2.y; Ws[10][tid]=w2.z; Ws[11][tid]=w2.w;
    Ws[12][tid]=w3.x; Ws[13][tid]=w3.y; Ws[14][tid]=w3.z; Ws[15][tid]=w3.w;
    __syncthreads();
    if (k0 + 16 < ke) gload(k0 + 16);  // prefetch overlaps compute
#pragma unroll
    for (int kk = 0; kk < 16; ++kk) {
      f32x4 al = *(const f32x4*)&As[kk][ty * 8];
      f32x4 ah = *(const f32x4*)&As[kk][ty * 8 + 4];
      f32x4 b0 = *(const f32x4*)&Ws[kk][tx * 4];
      f32x4 b1 = *(const f32x4*)&Ws[kk][64 + tx * 4];
      f32x4 b2 = *(const f32x4*)&Ws[kk][128 + tx * 4];
      f32x4 b3 = *(const f32x4*)&Ws[kk][192 + tx * 4];
#pragma unroll
      for (int i = 0; i < 4; ++i) {
        f32x4 sl = splat4(al[i]), sh = splat4(ah[i]);
        acc[i][0] += sl * b0; acc[i][1] += sl * b1;
        acc[i][2] += sl * b2; acc[i][3] += sl * b3;
        acc[i+4][0] += sh * b0; acc[i+4][1] += sh * b1;
        acc[i+4][2] += sh * b2; acc[i+4][3] += sh * b3;
      }
    }
  }
  bool single = (gridDim.z == 1);
#pragma unroll
  for (int i = 0; i < 8; ++i) {
    int row = bm + ty * 8 + i;
    float* crow = C + (size_t)row * N;
#pragma unroll
    for (int j = 0; j < 4; ++j) {
      int c = bn + j * 64 + tx * 4;
      if (c < N) {
        if (single) *(f32x4*)(crow + c) = acc[i][j];
        else {
          atomicAdd(crow + c + 0, acc[i][j][0]); atomicAdd(crow + c + 1, acc[i][j][1]);
          atomicAdd(crow + c + 2, acc[i][j][2]); atomicAdd(crow + c + 3, acc[i][j][3]);
        }
      }
    }
  }
}

// ---------------- fp32 GEMM v3 (skinny shapes): 128x128, 8x8 ----------------
__global__ __launch_bounds__(256) void gemm_f32_v3(
    const float* __restrict__ A, const float* __restrict__ W,
    float* __restrict__ C, int M, int N, int K) {
  __shared__ float As[16][132];
  __shared__ float Ws[16][132];
  int tid = threadIdx.x;
  int bm = blockIdx.y * 128, bn = blockIdx.x * 128;
  int kper = K / gridDim.z;
  int kb = blockIdx.z * kper, ke = kb + kper;
  int lr = tid >> 1;
  int lh = (tid & 1) * 8;
  int tx = tid & 15, ty = tid >> 4;
  bool wok = (bn + lr < N);
  const float* arow = A + (size_t)(bm + lr) * K + lh;
  const float* wrow = W + (size_t)(bn + lr) * K + lh;
  float4 a0, a1, w0, w1;
  auto gload = [&](int k0) {
    a0 = *(const float4*)(arow + k0);
    a1 = *(const float4*)(arow + k0 + 4);
    w0 = make_float4(0.f, 0.f, 0.f, 0.f); w1 = w0;
    if (wok) {
      w0 = *(const float4*)(wrow + k0);
      w1 = *(const float4*)(wrow + k0 + 4);
    }
  };
  f32x4 acc0[8] = {}, acc1[8] = {};
  gload(kb);
  for (int k0 = kb; k0 < ke; k0 += 16) {
    __syncthreads();
    As[lh+0][lr]=a0.x; As[lh+1][lr]=a0.y; As[lh+2][lr]=a0.z; As[lh+3][lr]=a0.w;
    As[lh+4][lr]=a1.x; As[lh+5][lr]=a1.y; As[lh+6][lr]=a1.z; As[lh+7][lr]=a1.w;
    Ws[lh+0][lr]=w0.x; Ws[lh+1][lr]=w0.y; Ws[lh+2][lr]=w0.z; Ws[lh+3][lr]=w0.w;
    Ws[lh+4][lr]=w1.x; Ws[lh+5][lr]=w1.y; Ws[lh+6][lr]=w1.z; Ws[lh+7][lr]=w1.w;
    __syncthreads();
    if (k0 + 16 < ke) gload(k0 + 16);
#pragma unroll
    for (int kk = 0; kk < 16; ++kk) {
      f32x4 b0 = *(const f32x4*)&Ws[kk][tx * 4];
      f32x4 b1 = *(const f32x4*)&Ws[kk][64 + tx * 4];
      f32x4 al = *(const f32x4*)&As[kk][ty * 8];
      f32x4 ah = *(const f32x4*)&As[kk][ty * 8 + 4];
#pragma unroll
      for (int i = 0; i < 4; ++i) {
        acc0[i]     += splat4(al[i]) * b0;
        acc1[i]     += splat4(al[i]) * b1;
        acc0[i + 4] += splat4(ah[i]) * b0;
        acc1[i + 4] += splat4(ah[i]) * b1;
      }
    }
  }
  bool single = (gridDim.z == 1);
#pragma unroll
  for (int i = 0; i < 8; ++i) {
    int row = bm + ty * 8 + i;
    float* crow = C + (size_t)row * N;
    int c0 = bn + tx * 4, c1 = bn + 64 + tx * 4;
    if (c0 + 3 < N) {
      if (single) *(f32x4*)(crow + c0) = acc0[i];
      else {
        atomicAdd(crow + c0 + 0, acc0[i][0]); atomicAdd(crow + c0 + 1, acc0[i][1]);
        atomicAdd(crow + c0 + 2, acc0[i][2]); atomicAdd(crow + c0 + 3, acc0[i][3]);
      }
    }
    if (c1 + 3 < N) {
      if (single) *(f32x4*)(crow + c1) = acc1[i];
      else {
        atomicAdd(crow + c1 + 0, acc1[i][0]); atomicAdd(crow + c1 + 1, acc1[i][1]);
        atomicAdd(crow + c1 + 2, acc1[i][2]); atomicAdd(crow + c1 + 3, acc1[i][3]);
      }
    }
  }
}

// ---------------- bf16 MFMA GEMM (value path) ----------------
__global__ __launch_bounds__(256) void gemm_bf16_kernel(
    const unsigned short* __restrict__ A, const unsigned short* __restrict__ W,
    float* __restrict__ C, int M, int N, int K, int lda, int ldb, int ldc) {
  __shared__ unsigned short As[128 * 64];
  __shared__ unsigned short Ws[128 * 64];
  int tid = threadIdx.x;
  int bm = blockIdx.y * 128, bn = blockIdx.x * 128;
  int kper = K / gridDim.z;
  int k_begin = blockIdx.z * kper;
  int k_end = k_begin + kper;
  int wv = tid >> 6, lane = tid & 63;
  int wrow = (wv >> 1) * 64, wcol = (wv & 1) * 64;
  int lrow = lane & 15, quad = lane >> 4;

  f32x4 acc[4][4] = {};

  for (int k0 = k_begin; k0 < k_end; k0 += 64) {
    __syncthreads();
#pragma unroll
    for (int it = 0; it < 4; ++it) {
      int s = it * 256 + tid;
      int r = s >> 3;
      int q = (s & 7) ^ (r & 7);
      const unsigned short* ga = A + (size_t)(bm + r) * lda + k0 + q * 8;
      const unsigned short* gw = W + (size_t)(bn + r) * ldb + k0 + q * 8;
      __builtin_amdgcn_global_load_lds((const __attribute__((address_space(1))) void*)ga,
                                       (__attribute__((address_space(3))) void*)&As[s * 8], 16, 0, 0);
      __builtin_amdgcn_global_load_lds((const __attribute__((address_space(1))) void*)gw,
                                       (__attribute__((address_space(3))) void*)&Ws[s * 8], 16, 0, 0);
    }
    __syncthreads();
#pragma unroll
    for (int ks = 0; ks < 2; ++ks) {
      bf16x8 af[4], wf[4];
#pragma unroll
      for (int i = 0; i < 4; ++i) {
        int ra = wrow + i * 16 + lrow;
        int qa = (ks * 4 + quad) ^ (ra & 7);
        af[i] = *(const bf16x8*)&As[(ra * 8 + qa) * 8];
        int rw = wcol + i * 16 + lrow;
        int qw = (ks * 4 + quad) ^ (rw & 7);
        wf[i] = *(const bf16x8*)&Ws[(rw * 8 + qw) * 8];
      }
#pragma unroll
      for (int i = 0; i < 4; ++i)
#pragma unroll
        for (int j = 0; j < 4; ++j)
          acc[i][j] = __builtin_amdgcn_mfma_f32_16x16x32_bf16(af[i], wf[j], acc[i][j], 0, 0, 0);
    }
  }
  bool single = (gridDim.z == 1);
#pragma unroll
  for (int i = 0; i < 4; ++i)
#pragma unroll
    for (int j = 0; j < 4; ++j)
#pragma unroll
      for (int r = 0; r < 4; ++r) {
        int row = bm + wrow + i * 16 + quad * 4 + r;
        int col = bn + wcol + j * 16 + lrow;
        float v = acc[i][j][r];
        if (single) C[(size_t)row * ldc + col] = v;
        else atomicAdd(&C[(size_t)row * ldc + col], v);
      }
}

// ---------------- conversions (split-bf16 aug) ----------------
__global__ __launch_bounds__(256) void conv_augA_kernel(
    const float* __restrict__ src, unsigned short* __restrict__ dst,
    int total, int K, int sld) {
  int i = blockIdx.x * 256 + threadIdx.x;
  if (i >= total) return;
  int m = i / K, k = i - m * K;
  float f = src[(size_t)m * sld + k];
  unsigned short hi = f2bf(f);
  unsigned short lo = f2bf(f - bf2f(hi));
  size_t o = ((size_t)m * K + k) * 3;
  dst[o] = hi; dst[o + 1] = lo; dst[o + 2] = hi;
}
__global__ __launch_bounds__(256) void conv_augW_kernel(
    const float* __restrict__ src, unsigned short* __restrict__ dst,
    int rows, int total, int K, int sld) {
  int i = blockIdx.x * 256 + threadIdx.x;
  if (i >= total) return;
  int n = i / K, k = i - n * K;
  unsigned short hi = 0, lo = 0;
  if (n < rows) {
    float f = src[(size_t)n * sld + k];
    hi = f2bf(f);
    lo = f2bf(f - bf2f(hi));
  }
  size_t o = ((size_t)n * K + k) * 3;
  dst[o] = hi; dst[o + 1] = hi; dst[o + 2] = lo;
}

// ---------------- conv1d(4-tap, causal) + SiLU ----------------
__global__ __launch_bounds__(256) void conv_silu_kernel(
    const float* __restrict__ zxbcdt, const float* __restrict__ conv_w,
    const float* __restrict__ conv_b, float* __restrict__ xBC) {
  int idx = blockIdx.x * 256 + threadIdx.x;
  if (idx >= L * CONVCH) return;
  int l = idx / CONVCH, c = idx - l * CONVCH;
  float acc = conv_b[c];
#pragma unroll
  for (int k = 0; k < 4; ++k) {
    int ls = l - 3 + k;
    if (ls >= 0) acc += zxbcdt[(size_t)ls * INDIM + DINNER + c] * conv_w[c * 4 + k];
  }
  xBC[idx] = acc / (1.f + expf(-acc));
}

// ---------------- dt / logdA ----------------
__global__ __launch_bounds__(256) void dt_kernel(
    const float* __restrict__ zxbcdt, const float* __restrict__ dt_bias,
    const float* __restrict__ A_log, float* __restrict__ dt, float* __restrict__ logdA) {
  int idx = blockIdx.x * 256 + threadIdx.x;
  int l = idx >> 5, h = idx & 31;
  float xv = zxbcdt[(size_t)l * INDIM + (INDIM - MNH) + h] + dt_bias[h];
  float sp = fmaxf(xv, 0.f) + log1pf(expf(-fabsf(xv)));
  dt[idx] = sp;
  logdA[idx] = sp * -expf(A_log[h]);
}

// ---------------- lcd ----------------
__global__ __launch_bounds__(256) void lcd_kernel(
    const float* __restrict__ logdA, float* __restrict__ lcd) {
  int i = blockIdx.x * 256 + threadIdx.x;
  if (i >= NCH * MNH) return;
  int c = i >> 5, h = i & 31;
  float s = 0.f;
  for (int t = 0; t < CHUNK; ++t) {
    s += logdA[(c * CHUNK + t) * MNH + h];
    lcd[(size_t)i * CHUNK + t] = s;
  }
}

// ---------------- G[c][t][s] = C_t . B_s ----------------
__global__ __launch_bounds__(256) void chunk_G_kernel(
    const float* __restrict__ xBC, float* __restrict__ G) {
  int c = blockIdx.x, tid = threadIdx.x;
  __shared__ float BsT[64][68];
  __shared__ float Cs[64][65];
  int t = tid >> 2, q = tid & 3;
  const float* row = xBC + (size_t)(c * 64 + t) * CONVCH + DINNER;
#pragma unroll
  for (int j = 0; j < 16; j += 4) {
    float4 b = *(const float4*)(row + q * 16 + j);
    BsT[q * 16 + j + 0][t] = b.x; BsT[q * 16 + j + 1][t] = b.y;
    BsT[q * 16 + j + 2][t] = b.z; BsT[q * 16 + j + 3][t] = b.w;
    float4 cv = *(const float4*)(row + 64 + q * 16 + j);
    Cs[t][q * 16 + j + 0] = cv.x; Cs[t][q * 16 + j + 1] = cv.y;
    Cs[t][q * 16 + j + 2] = cv.z; Cs[t][q * 16 + j + 3] = cv.w;
  }
  __syncthreads();
  int s0 = q * 16;
  f32x4 g0 = {}, g1 = {}, g2 = {}, g3 = {};
  for (int n = 0; n < 64; ++n) {
    f32x4 cv = splat4(Cs[t][n]);
    g0 += cv * *(const f32x4*)&BsT[n][s0];
    g1 += cv * *(const f32x4*)&BsT[n][s0 + 4];
    g2 += cv * *(const f32x4*)&BsT[n][s0 + 8];
    g3 += cv * *(const f32x4*)&BsT[n][s0 + 12];
  }
  float* gp = G + ((size_t)c * 64 + t) * 64 + s0;
  *(f32x4*)gp = g0; *(f32x4*)(gp + 4) = g1; *(f32x4*)(gp + 8) = g2; *(f32x4*)(gp + 12) = g3;
}

// ---------------- scan pass A ----------------
__global__ __launch_bounds__(256) void scan_local_kernel(
    const float* __restrict__ xBC, const float* __restrict__ dt,
    const float* __restrict__ lcd, float* __restrict__ hstate) {
  int c = blockIdx.x >> 5, h = blockIdx.x & 31;
  int tid = threadIdx.x;
  __shared__ float Bs[64][68];
  __shared__ float xss[64][36];
  __shared__ float w2s[64];
  int t0 = c * CHUNK;
  int t = tid >> 2, q = tid & 3;
  const float* row = xBC + (size_t)(t0 + t) * CONVCH;
#pragma unroll
  for (int j = 0; j < 16; j += 4)
    *(float4*)&Bs[t][q * 16 + j] = *(const float4*)(row + DINNER + q * 16 + j);
  if (q < 2) {
#pragma unroll
    for (int j = 0; j < 16; j += 4)
      *(float4*)&xss[t][q * 16 + j] = *(const float4*)(row + h * 32 + q * 16 + j);
  }
  if (tid < 64) {
    const float* lc = lcd + ((size_t)c * 32 + h) * CHUNK;
    w2s[tid] = expf(lc[63] - lc[tid]) * dt[(t0 + tid) * MNH + h];
  }
  __syncthreads();
  int n = tid >> 2, pg = (tid & 3) * 8;
  f32x4 h0 = {}, h1 = {};
  for (int s = 0; s < 64; ++s) {
    f32x4 wb = splat4(w2s[s] * Bs[s][n]);
    h0 += wb * *(const f32x4*)&xss[s][pg];
    h1 += wb * *(const f32x4*)&xss[s][pg + 4];
  }
  float* hp = hstate + ((size_t)c * 32 + h) * 2048 + n * 32 + pg;
  *(f32x4*)hp = h0; *(f32x4*)(hp + 4) = h1;
}

// ---------------- scan pass B ----------------
__global__ __launch_bounds__(256) void scan_combine_kernel(
    float* __restrict__ hstate, const float* __restrict__ lcd) {
  int i = blockIdx.x * 256 + threadIdx.x;
  int h = i >> 11;
  float H = 0.f;
  for (int c = 0; c < NCH; ++c) {
    float hl = hstate[(size_t)c * 65536 + i];
    hstate[(size_t)c * 65536 + i] = H;
    float P = expf(lcd[((size_t)c * 32 + h) * CHUNK + CHUNK - 1]);
    H = H * P + hl;
  }
}

// ---------------- scan pass C ----------------
__global__ __launch_bounds__(256) void scan_y_kernel(
    const float* __restrict__ xBC, const float* __restrict__ G,
    const float* __restrict__ dt, const float* __restrict__ lcd,
    const float* __restrict__ hstate, float* __restrict__ y) {
  int c = blockIdx.x >> 5, h = blockIdx.x & 31;
  int tid = threadIdx.x;
  __shared__ float Ms[64][65];
  __shared__ float Cs[64][65];
  __shared__ float xss[64][36];
  __shared__ float Hss[64][36];
  __shared__ float lcds[64], dts[64];
  int t0 = c * CHUNK;
  int t = tid >> 2, q = tid & 3;
  const float* row = xBC + (size_t)(t0 + t) * CONVCH;
#pragma unroll
  for (int j = 0; j < 16; j += 4) {
    float4 cv = *(const float4*)(row + DINNER + 64 + q * 16 + j);
    Cs[t][q * 16 + j + 0] = cv.x; Cs[t][q * 16 + j + 1] = cv.y;
    Cs[t][q * 16 + j + 2] = cv.z; Cs[t][q * 16 + j + 3] = cv.w;
  }
  if (q < 2) {
#pragma unroll
    for (int j = 0; j < 16; j += 4)
      *(float4*)&xss[t][q * 16 + j] = *(const float4*)(row + h * 32 + q * 16 + j);
  }
  {
    const float* gp = G + ((size_t)c * 64 + t) * 64 + q * 16;
#pragma unroll
    for (int j = 0; j < 16; j += 4) {
      float4 g = *(const float4*)(gp + j);
      Ms[t][q * 16 + j + 0] = g.x; Ms[t][q * 16 + j + 1] = g.y;
      Ms[t][q * 16 + j + 2] = g.z; Ms[t][q * 16 + j + 3] = g.w;
    }
  }
  {
    const float* hp = hstate + ((size_t)c * 32 + h) * 2048 + tid * 8;
    int n = tid >> 2, p0 = (tid & 3) * 8;
    *(float4*)&Hss[n][p0]     = *(const float4*)hp;
    *(float4*)&Hss[n][p0 + 4] = *(const float4*)(hp + 4);
  }
  if (tid < 64) {
    lcds[tid] = lcd[((size_t)c * 32 + h) * CHUNK + tid];
    dts[tid]  = dt[(t0 + tid) * MNH + h];
  }
  __syncthreads();
  {
    int s0 = q * 16;
#pragma unroll
    for (int j = 0; j < 16; ++j) {
      int s = s0 + j;
      float m = (s <= t) ? expf(lcds[t] - lcds[s]) * dts[s] * Ms[t][s] : 0.f;
      Ms[t][s] = m;
    }
  }
  __syncthreads();
  int pg = q * 8;
  f32x4 y0 = {}, y1 = {}, a0 = {}, a1 = {};
  for (int s = 0; s < 64; ++s) {
    f32x4 m = splat4(Ms[t][s]);
    y0 += m * *(const f32x4*)&xss[s][pg];
    y1 += m * *(const f32x4*)&xss[s][pg + 4];
  }
  for (int n = 0; n < 64; ++n) {
    f32x4 cn = splat4(Cs[t][n]);
    a0 += cn * *(const f32x4*)&Hss[n][pg];
    a1 += cn * *(const f32x4*)&Hss[n][pg + 4];
  }
  f32x4 cd = splat4(expf(lcds[t]));
  y0 += cd * a0; y1 += cd * a1;
  float* yp = y + (size_t)(t0 + t) * DINNER + h * 32 + pg;
  *(f32x4*)yp = y0; *(f32x4*)(yp + 4) = y1;
}

// ---------------- gate + RMSNorm ----------------
__global__ __launch_bounds__(256) void gatenorm_kernel(
    const float* __restrict__ y_ssm, const float* __restrict__ xBC,
    const float* __restrict__ zxbcdt, const float* __restrict__ Dv,
    const float* __restrict__ norm_w, float* __restrict__ out) {
  int l = blockIdx.x, tid = threadIdx.x;
  float vals[4];
  float ss = 0.f;
#pragma unroll
  for (int i = 0; i < 4; ++i) {
    int d = tid + i * 256;
    int h = d >> 5;
    float v = y_ssm[(size_t)l * DINNER + d] + Dv[h] * xBC[(size_t)l * CONVCH + d];
    float z = zxbcdt[(size_t)l * INDIM + d];
    v *= z / (1.f + expf(-z));
    vals[i] = v;
    ss += v * v;
  }
#pragma unroll
  for (int off = 32; off > 0; off >>= 1) ss += __shfl_xor(ss, off);
  __shared__ float sred[4];
  if ((tid & 63) == 0) sred[tid >> 6] = ss;
  __syncthreads();
  float tot = sred[0] + sred[1] + sred[2] + sred[3];
  float scale = rsqrtf(tot * (1.f / 1024.f) + 1e-5f);
#pragma unroll
  for (int i = 0; i < 4; ++i) {
    int d = tid + i * 256;
    out[(size_t)l * DINNER + d] = vals[i] * scale * norm_w[d];
  }
}

// ---------------- per-row top-64 radix select ----------------
__global__ __launch_bounds__(256) void topk_kernel(
    const float* __restrict__ scores, int* __restrict__ out_idx) {
  int l = blockIdx.x, tid = threadIdx.x;
  if (l < 64) {
    if (tid < 64) out_idx[l * 64 + tid] = tid;
    return;
  }
  int n = l + 1;
  const float* row = scores + (size_t)l * L;
  __shared__ int hist[256];
  __shared__ unsigned sel_prefix;
  __shared__ int sel_remaining;
  __shared__ int cnt_g, cnt_e;
  __shared__ int eq_list[128];
  if (tid == 0) { cnt_g = 0; cnt_e = 0; }
  unsigned prefix = 0;
  int remaining = 64;
  for (int pass = 0; pass < 4; ++pass) {
    int shift = 24 - 8 * pass;
    unsigned himask = (pass == 0) ? 0u : (0xFFFFFFFFu << (shift + 8));
    hist[tid] = 0;
    __syncthreads();
    for (int j = tid; j < n; j += 256) {
      unsigned u = __float_as_uint(row[j]);
      unsigned key = (u & 0x80000000u) ? ~u : (u | 0x80000000u);
      if (((key ^ prefix) & himask) == 0)
        atomicAdd(&hist[(key >> shift) & 255], 1);
    }
    __syncthreads();
    if (tid == 0) {
      int cum = 0, b = 255;
      for (; b >= 0; --b) {
        cum += hist[b];
        if (cum >= remaining) break;
      }
      sel_prefix = prefix | ((unsigned)b << shift);
      sel_remaining = remaining - (cum - hist[b]);
    }
    __syncthreads();
    prefix = sel_prefix;
    remaining = sel_remaining;
    __syncthreads();
  }
  unsigned T = prefix;
  for (int j = tid; j < n; j += 256) {
    unsigned u = __float_as_uint(row[j]);
    unsigned key = (u & 0x80000000u) ? ~u : (u | 0x80000000u);
    if (key > T) {
      int p = atomicAdd(&cnt_g, 1);
      out_idx[l * 64 + p] = j;
    } else if (key == T) {
      int p = atomicAdd(&cnt_e, 1);
      if (p < 128) eq_list[p] = j;
    }
  }
  __syncthreads();
  if (tid == 0) {
    int G = cnt_g;
    int E = remaining;
    int m = cnt_e < 128 ? cnt_e : 128;
    for (int e = 0; e < E; ++e) {
      int best = 0, bj = 0x7fffffff;
      for (int i = 0; i < m; ++i)
        if (eq_list[i] < bj) { bj = eq_list[i]; best = i; }
      out_idx[l * 64 + G + e] = bj;
      eq_list[best] = 0x7fffffff;
    }
  }
}

// ---------------- RoPE + pack q_final/k_final ----------------
__global__ __launch_bounds__(128) void rope_pack_kernel(
    const float* __restrict__ q_content, const float* __restrict__ q_rope_lin,
    const float* __restrict__ kv, const float* __restrict__ k_rope_lin,
    float* __restrict__ q_final, float* __restrict__ k_final) {
  int l = blockIdx.x, tid = threadIdx.x;
  __shared__ float s_s[16], s_c[16];
  if (tid < 16) {
    float inv = powf(10000.f, -(float)tid / 16.f);
    float ang = (float)l * inv;
    s_s[tid] = sinf(ang);
    s_c[tid] = cosf(ang);
  }
  __syncthreads();
  for (int e = tid; e < NH * 96; e += 128) {
    int hh = e / 96, d = e - hh * 96;
    float qv, kvv;
    if (d < 64) {
      qv  = q_content[(size_t)l * 1024 + hh * 64 + d];
      kvv = kv[(size_t)l * 2048 + hh * 64 + d];
    } else {
      int r = d - 64;
      if (r < 16) {
        float q1 = q_rope_lin[(size_t)l * 512 + hh * 32 + r];
        float q2 = q_rope_lin[(size_t)l * 512 + hh * 32 + 16 + r];
        qv = q1 * s_c[r] - q2 * s_s[r];
        float k1 = k_rope_lin[(size_t)l * 128 + r];
        float k2 = k_rope_lin[(size_t)l * 128 + 16 + r];
        kvv = k1 * s_c[r] - k2 * s_s[r];
      } else {
        int rr = r - 16;
        float q1 = q_rope_lin[(size_t)l * 512 + hh * 32 + rr];
        float q2 = q_rope_lin[(size_t)l * 512 + hh * 32 + 16 + rr];
        qv = q1 * s_s[rr] + q2 * s_c[rr];
        float k1 = k_rope_lin[(size_t)l * 128 + rr];
        float k2 = k_rope_lin[(size_t)l * 128 + 16 + rr];
        kvv = k1 * s_s[rr] + k2 * s_c[rr];
      }
    }
    q_final[(size_t)l * 1536 + e] = qv;
    k_final[(size_t)l * 1536 + e] = kvv;
  }
}

// ---------------- sparse attention ----------------
__global__ __launch_bounds__(256) void attn_kernel(
    const float* __restrict__ q_final, const float* __restrict__ k_final,
    const float* __restrict__ kv, const int* __restrict__ idx,
    unsigned short* __restrict__ attn_aug) {
  int w = blockIdx.x * 4 + (threadIdx.x >> 6);
  int lane = threadIdx.x & 63;
  int l = w >> 4, h = w & 15;
  int ik = idx[l * 64 + lane];
  const float4* qp = (const float4*)(q_final + (size_t)l * 1536 + h * 96);
  const float4* kp = (const float4*)(k_final + (size_t)ik * 1536 + h * 96);
  float dot = 0.f;
#pragma unroll
  for (int j = 0; j < 24; ++j) {
    float4 q4 = qp[j], k4 = kp[j];
    dot += q4.x * k4.x + q4.y * k4.y + q4.z * k4.z + q4.w * k4.w;
  }
  float logit = dot * 0.10206207261596575f;
  float m = logit;
#pragma unroll
  for (int off = 32; off > 0; off >>= 1) m = fmaxf(m, __shfl_xor(m, off));
  float e = expf(logit - m);
  float ssum = e;
#pragma unroll
  for (int off = 32; off > 0; off >>= 1) ssum += __shfl_xor(ssum, off);
  float wgt = e / ssum;
  float acc = 0.f;
  const float* vbase = kv + 1024 + h * 64 + lane;
  for (int k = 0; k < 64; ++k) {
    float wk = __shfl(wgt, k);
    int kk = __shfl(ik, k);
    acc += wk * vbase[(size_t)kk * 2048];
  }
  unsigned short hi = f2bf(acc);
  unsigned short lo = f2bf(acc - bf2f(hi));
  size_t o = ((size_t)l * 1024 + h * 64 + lane) * 3;
  attn_aug[o] = hi; attn_aug[o + 1] = lo; attn_aug[o + 2] = hi;
}

// ---------------- host ----------------
extern "C" void kernel_launch(void* const* d_in, const int* in_sizes, int n_in,
                              void* d_out, int out_size, void* d_ws, size_t ws_size,
                              hipStream_t stream) {
  const float* x          = (const float*)d_in[0];
  const float* idx_in_w   = (const float*)d_in[1];
  const float* idx_conv_w = (const float*)d_in[2];
  const float* idx_conv_b = (const float*)d_in[3];
  const float* idx_dt_b   = (const float*)d_in[4];
  const float* idx_A_log  = (const float*)d_in[5];
  const float* idx_D      = (const float*)d_in[6];
  const float* idx_norm_w = (const float*)d_in[7];
  const float* idx_out_w  = (const float*)d_in[8];
  const float* idx_q_w    = (const float*)d_in[9];
  const float* idx_k_w    = (const float*)d_in[10];
  const float* q_down_w   = (const float*)d_in[11];
  const float* q_up_w     = (const float*)d_in[12];
  const float* q_rope_w   = (const float*)d_in[13];
  const float* kv_down_w  = (const float*)d_in[14];
  const float* kv_up_w    = (const float*)d_in[15];
  const float* k_rope_w   = (const float*)d_in[16];
  const float* out_w      = (const float*)d_in[17];
  float* out = (float*)d_out;

  // ---- workspace arena ----
  float* p = (float*)d_ws;
  float* segA = p; p += 4521984;
  float* segB = p; p += 2359296;
  float* dtb = p; p += 65536;
  float* logdA = p; p += 65536;
  float* lcdb = p; p += 65536;
  int*   idxb = (int*)p; p += 131072;
  float* segD = p; p += 4194304;
  float* segE = p; p += 3145728;
  float* segG = p; p += 3145728;
  float* segH = p; p += 3145728;
  unsigned short* w_qdown_aug  = (unsigned short*)p; p += 196608;
  unsigned short* w_kvdown_aug = (unsigned short*)p; p += 196608;
  unsigned short* w_krope_aug  = (unsigned short*)p; p += 196608;
  unsigned short* w_qup_aug    = (unsigned short*)p; p += 196608;
  unsigned short* w_qrope_aug  = (unsigned short*)p; p += 98304;
  unsigned short* w_kvup_aug   = (unsigned short*)p; p += 393216;
  unsigned short* c_q_aug      = (unsigned short*)p; p += 393216;
  unsigned short* c_kv_aug     = (unsigned short*)p; p += 393216;
  float* Gbuf = p; p += 131072;

  float* zxbcdt   = segA;
  float* scores   = segA;
  float* q_cont   = segA;
  float* q_rope_l = segA + 2097152;
  unsigned short* w_outp_aug = (unsigned short*)segA;
  float* xBC      = segB;
  float* q_idx    = segB;
  float* k_idx    = segB + 131072;
  float* c_q      = segB + 262144;
  float* c_kv     = segB + 524288;
  float* k_rope_l = segB + 786432;
  float* y_ssm  = segD;
  float* hstate = segD + 2097152;
  float* kvb    = segD;
  unsigned short* x_aug    = (unsigned short*)segE;
  unsigned short* attn_aug = (unsigned short*)segE;
  float* y_norm  = segG;
  float* q_final = segG;
  float* x_mamba = segH;
  float* k_final = segH;

  dim3 blk(256);
  auto cdiv = [](int a, int b) { return (a + b - 1) / b; };
  auto gemmf4 = [&](const float* A, const float* W, float* C, int M, int N, int K, int S) {
    dim3 grid(cdiv(N, 256), M / 128, S);
    hipLaunchKernelGGL(gemm_f32_v4, grid, blk, 0, stream, A, W, C, M, N, K);
  };
  auto gemmf3 = [&](const float* A, const float* W, float* C, int M, int N, int K, int S) {
    dim3 grid(cdiv(N, 128), M / 128, S);
    hipLaunchKernelGGL(gemm_f32_v3, grid, blk, 0, stream, A, W, C, M, N, K);
  };
  auto gemmb = [&](const unsigned short* A, const unsigned short* W, float* C,
                   int M, int N, int K, int lda, int ldb, int ldc, int S) {
    dim3 grid(N / 128, M / 128, S);
    hipLaunchKernelGGL(gemm_bf16_kernel, grid, blk, 0, stream, A, W, C, M, N, K, lda, ldb, ldc);
  };
  auto caugA = [&](const float* s, unsigned short* d, int total, int K, int sld) {
    hipLaunchKernelGGL(conv_augA_kernel, dim3(cdiv(total, 256)), blk, 0, stream, s, d, total, K, sld);
  };
  auto caugW = [&](const float* s, unsigned short* d, int rows, int total, int K, int sld) {
    hipLaunchKernelGGL(conv_augW_kernel, dim3(cdiv(total, 256)), blk, 0, stream, s, d, rows, total, K, sld);
  };

  // ---- mamba branch + index path: FULL FP32 ----
  caugA(x, x_aug, 2048 * 1024, 1024, 1024);
  hipMemsetAsync(zxbcdt, 0, (size_t)L * INDIM * 4, stream);
  gemmf4(x, idx_in_w, zxbcdt, 2048, INDIM, 1024, 2);
  hipLaunchKernelGGL(conv_silu_kernel, dim3(cdiv(L * CONVCH, 256)), blk, 0, stream,
                     zxbcdt, idx_conv_w, idx_conv_b, xBC);
  hipLaunchKernelGGL(dt_kernel, dim3(L * MNH / 256), blk, 0, stream,
                     zxbcdt, idx_dt_b, idx_A_log, dtb, logdA);
  hipLaunchKernelGGL(lcd_kernel, dim3(4), blk, 0, stream, logdA, lcdb);
  hipLaunchKernelGGL(chunk_G_kernel, dim3(NCH), blk, 0, stream, xBC, Gbuf);
  hipLaunchKernelGGL(scan_local_kernel, dim3(NCH * MNH), blk, 0, stream,
                     xBC, dtb, lcdb, hstate);
  hipLaunchKernelGGL(scan_combine_kernel, dim3(256), blk, 0, stream, hstate, lcdb);
  hipLaunchKernelGGL(scan_y_kernel, dim3(NCH * MNH), blk, 0, stream,
                     xBC, Gbuf, dtb, lcdb, hstate, y_ssm);
  hipLaunchKernelGGL(gatenorm_kernel, dim3(L), blk, 0, stream,
                     y_ssm, xBC, zxbcdt, idx_D, idx_norm_w, y_norm);
  hipMemsetAsync(x_mamba, 0, 2097152 * 4, stream);
  gemmf4(y_norm, idx_out_w, x_mamba, 2048, 1024, 1024, 4);
  hipMemsetAsync(q_idx, 0, 131072 * 4, stream);
  hipMemsetAsync(k_idx, 0, 131072 * 4, stream);
  gemmf3(x_mamba, idx_q_w, q_idx, 2048, 64, 1024, 16);
  gemmf3(x, idx_k_w, k_idx, 2048, 64, 1024, 16);
  gemmf3(q_idx, k_idx, scores, 2048, 2048, 64, 1);
  hipLaunchKernelGGL(topk_kernel, dim3(L), blk, 0, stream, scores, idxb);

  // ---- attention value path: aug split-bf16 MFMA ----
  caugW(q_down_w, w_qdown_aug, 128, 128 * 1024, 1024, 1024);
  caugW(kv_down_w, w_kvdown_aug, 128, 128 * 1024, 1024, 1024);
  caugW(k_rope_w, w_krope_aug, 32, 128 * 1024, 1024, 1024);
  hipMemsetAsync(c_q, 0, 262144 * 4, stream);
  hipMemsetAsync(c_kv, 0, 262144 * 4, stream);
  hipMemsetAsync(k_rope_l, 0, 262144 * 4, stream);
  gemmb(x_aug, w_qdown_aug, c_q, 2048, 128, 3072, 3072, 3072, 128, 8);
  gemmb(x_aug, w_kvdown_aug, c_kv, 2048, 128, 3072, 3072, 3072, 128, 8);
  gemmb(x_aug, w_krope_aug, k_rope_l, 2048, 128, 3072, 3072, 3072, 128, 8);
  caugA(c_q, c_q_aug, 2048 * 128, 128, 128);
  caugA(c_kv, c_kv_aug, 2048 * 128, 128, 128);
  caugW(q_up_w, w_qup_aug, 1024, 1024 * 128, 128, 128);
  caugW(q_rope_w, w_qrope_aug, 512, 512 * 128, 128, 128);
  caugW(kv_up_w, w_kvup_aug, 2048, 2048 * 128, 128, 128);
  hipMemsetAsync(q_rope_l, 0, 1048576 * 4, stream);
  gemmb(c_q_aug, w_qup_aug, q_cont, 2048, 1024, 384, 384, 384, 1024, 1);
  gemmb(c_q_aug, w_qrope_aug, q_rope_l, 2048, 512, 384, 384, 384, 512, 2);
  gemmb(c_kv_aug, w_kvup_aug, kvb, 2048, 2048, 384, 384, 384, 2048, 1);
  hipLaunchKernelGGL(rope_pack_kernel, dim3(L), dim3(128), 0, stream,
                     q_cont, q_rope_l, kvb, k_rope_l, q_final, k_final);

  // ---- sparse attention + output projection ----
  caugW(out_w, w_outp_aug, 1024, 1024 * 1024, 1024, 1024);
  hipLaunchKernelGGL(attn_kernel, dim3(L * NH / 4), blk, 0, stream,
                     q_final, k_final, kvb, idxb, attn_aug);
  hipMemsetAsync(out, 0, (size_t)out_size * 4, stream);
  gemmb(attn_aug, w_outp_aug, out, 2048, 1024, 3072, 3072, 3072, 1024, 2);
}

// Round 11
// 858.530 us; speedup vs baseline: 1.4240x; 1.2534x over previous
//
#include <hip/hip_runtime.h>
#include <math.h>

// ---------------- constants ----------------
constexpr int L      = 2048;
constexpr int NH     = 16;
constexpr int DINNER = 1024;
constexpr int MNH    = 32;
constexpr int CONVCH = 1152;
constexpr int INDIM  = 2208;
constexpr int CHUNK  = 64;
constexpr int NCH    = 32;

using bf16x8 = __attribute__((ext_vector_type(8))) short;
using f32x4  = __attribute__((ext_vector_type(4))) float;

__device__ __forceinline__ f32x4 splat4(float x) { return (f32x4){x, x, x, x}; }

__device__ __forceinline__ unsigned short f2bf(float f) {
  unsigned u = __float_as_uint(f);
  return (unsigned short)((u + 0x7fffu + ((u >> 16) & 1u)) >> 16);
}
__device__ __forceinline__ float bf2f(unsigned short h) {
  return __uint_as_float((unsigned)h << 16);
}

// ---------------- fp32 GEMM v3 (index-critical path): 128x128, 8x8 ----------------
// LDS-pipe model: 16 ds_read_b128/CU/kk (~192cyc) vs 64cyc VALU -> 33% VALU
// ceiling (measured 34%). This is the structure's floor; used as-is.
__global__ __launch_bounds__(256) void gemm_f32_v3(
    const float* __restrict__ A, const float* __restrict__ W,
    float* __restrict__ C, int M, int N, int K) {
  __shared__ float As[16][132];
  __shared__ float Ws[16][132];
  int tid = threadIdx.x;
  int bm = blockIdx.y * 128, bn = blockIdx.x * 128;
  int kper = K / gridDim.z;
  int kb = blockIdx.z * kper, ke = kb + kper;
  int lr = tid >> 1;
  int lh = (tid & 1) * 8;
  int tx = tid & 15, ty = tid >> 4;
  bool wok = (bn + lr < N);
  const float* arow = A + (size_t)(bm + lr) * K + lh;
  const float* wrow = W + (size_t)(bn + lr) * K + lh;
  float4 a0, a1, w0, w1;
  auto gload = [&](int k0) {
    a0 = *(const float4*)(arow + k0);
    a1 = *(const float4*)(arow + k0 + 4);
    w0 = make_float4(0.f, 0.f, 0.f, 0.f); w1 = w0;
    if (wok) {
      w0 = *(const float4*)(wrow + k0);
      w1 = *(const float4*)(wrow + k0 + 4);
    }
  };
  f32x4 acc0[8] = {}, acc1[8] = {};
  gload(kb);
  for (int k0 = kb; k0 < ke; k0 += 16) {
    __syncthreads();
    As[lh+0][lr]=a0.x; As[lh+1][lr]=a0.y; As[lh+2][lr]=a0.z; As[lh+3][lr]=a0.w;
    As[lh+4][lr]=a1.x; As[lh+5][lr]=a1.y; As[lh+6][lr]=a1.z; As[lh+7][lr]=a1.w;
    Ws[lh+0][lr]=w0.x; Ws[lh+1][lr]=w0.y; Ws[lh+2][lr]=w0.z; Ws[lh+3][lr]=w0.w;
    Ws[lh+4][lr]=w1.x; Ws[lh+5][lr]=w1.y; Ws[lh+6][lr]=w1.z; Ws[lh+7][lr]=w1.w;
    __syncthreads();
    if (k0 + 16 < ke) gload(k0 + 16);
#pragma unroll
    for (int kk = 0; kk < 16; ++kk) {
      f32x4 b0 = *(const f32x4*)&Ws[kk][tx * 4];
      f32x4 b1 = *(const f32x4*)&Ws[kk][64 + tx * 4];
      f32x4 al = *(const f32x4*)&As[kk][ty * 8];
      f32x4 ah = *(const f32x4*)&As[kk][ty * 8 + 4];
#pragma unroll
      for (int i = 0; i < 4; ++i) {
        acc0[i]     += splat4(al[i]) * b0;
        acc1[i]     += splat4(al[i]) * b1;
        acc0[i + 4] += splat4(ah[i]) * b0;
        acc1[i + 4] += splat4(ah[i]) * b1;
      }
    }
  }
  bool single = (gridDim.z == 1);
#pragma unroll
  for (int i = 0; i < 8; ++i) {
    int row = bm + ty * 8 + i;
    float* crow = C + (size_t)row * N;
    int c0 = bn + tx * 4, c1 = bn + 64 + tx * 4;
    if (c0 + 3 < N) {
      if (single) *(f32x4*)(crow + c0) = acc0[i];
      else {
        atomicAdd(crow + c0 + 0, acc0[i][0]); atomicAdd(crow + c0 + 1, acc0[i][1]);
        atomicAdd(crow + c0 + 2, acc0[i][2]); atomicAdd(crow + c0 + 3, acc0[i][3]);
      }
    }
    if (c1 + 3 < N) {
      if (single) *(f32x4*)(crow + c1) = acc1[i];
      else {
        atomicAdd(crow + c1 + 0, acc1[i][0]); atomicAdd(crow + c1 + 1, acc1[i][1]);
        atomicAdd(crow + c1 + 2, acc1[i][2]); atomicAdd(crow + c1 + 3, acc1[i][3]);
      }
    }
  }
}

// ---------------- 1024x1024 transpose (for Wq' = idx_q_w @ idx_out_w fold) ----------------
__global__ __launch_bounds__(256) void transpose1024_kernel(
    const float* __restrict__ src, float* __restrict__ dst) {
  __shared__ float t[32][33];
  int bx = blockIdx.x & 31, by = blockIdx.x >> 5;
  int tx = threadIdx.x & 31, ty8 = threadIdx.x >> 5;
  for (int r = ty8; r < 32; r += 8)
    t[r][tx] = src[(size_t)(by * 32 + r) * 1024 + bx * 32 + tx];
  __syncthreads();
  for (int r = ty8; r < 32; r += 8)
    dst[(size_t)(bx * 32 + r) * 1024 + by * 32 + tx] = t[tx][r];
}

// ---------------- bf16 MFMA GEMM (value path) ----------------
__global__ __launch_bounds__(256) void gemm_bf16_kernel(
    const unsigned short* __restrict__ A, const unsigned short* __restrict__ W,
    float* __restrict__ C, int M, int N, int K, int lda, int ldb, int ldc) {
  __shared__ unsigned short As[128 * 64];
  __shared__ unsigned short Ws[128 * 64];
  int tid = threadIdx.x;
  int bm = blockIdx.y * 128, bn = blockIdx.x * 128;
  int kper = K / gridDim.z;
  int k_begin = blockIdx.z * kper;
  int k_end = k_begin + kper;
  int wv = tid >> 6, lane = tid & 63;
  int wrow = (wv >> 1) * 64, wcol = (wv & 1) * 64;
  int lrow = lane & 15, quad = lane >> 4;

  f32x4 acc[4][4] = {};

  for (int k0 = k_begin; k0 < k_end; k0 += 64) {
    __syncthreads();
#pragma unroll
    for (int it = 0; it < 4; ++it) {
      int s = it * 256 + tid;
      int r = s >> 3;
      int q = (s & 7) ^ (r & 7);
      const unsigned short* ga = A + (size_t)(bm + r) * lda + k0 + q * 8;
      const unsigned short* gw = W + (size_t)(bn + r) * ldb + k0 + q * 8;
      __builtin_amdgcn_global_load_lds((const __attribute__((address_space(1))) void*)ga,
                                       (__attribute__((address_space(3))) void*)&As[s * 8], 16, 0, 0);
      __builtin_amdgcn_global_load_lds((const __attribute__((address_space(1))) void*)gw,
                                       (__attribute__((address_space(3))) void*)&Ws[s * 8], 16, 0, 0);
    }
    __syncthreads();
#pragma unroll
    for (int ks = 0; ks < 2; ++ks) {
      bf16x8 af[4], wf[4];
#pragma unroll
      for (int i = 0; i < 4; ++i) {
        int ra = wrow + i * 16 + lrow;
        int qa = (ks * 4 + quad) ^ (ra & 7);
        af[i] = *(const bf16x8*)&As[(ra * 8 + qa) * 8];
        int rw = wcol + i * 16 + lrow;
        int qw = (ks * 4 + quad) ^ (rw & 7);
        wf[i] = *(const bf16x8*)&Ws[(rw * 8 + qw) * 8];
      }
#pragma unroll
      for (int i = 0; i < 4; ++i)
#pragma unroll
        for (int j = 0; j < 4; ++j)
          acc[i][j] = __builtin_amdgcn_mfma_f32_16x16x32_bf16(af[i], wf[j], acc[i][j], 0, 0, 0);
    }
  }
  bool single = (gridDim.z == 1);
#pragma unroll
  for (int i = 0; i < 4; ++i)
#pragma unroll
    for (int j = 0; j < 4; ++j)
#pragma unroll
      for (int r = 0; r < 4; ++r) {
        int row = bm + wrow + i * 16 + quad * 4 + r;
        int col = bn + wcol + j * 16 + lrow;
        float v = acc[i][j][r];
        if (single) C[(size_t)row * ldc + col] = v;
        else atomicAdd(&C[(size_t)row * ldc + col], v);
      }
}

// ---------------- conversions (split-bf16 aug) ----------------
__global__ __launch_bounds__(256) void conv_augA_kernel(
    const float* __restrict__ src, unsigned short* __restrict__ dst,
    int total, int K, int sld) {
  int i = blockIdx.x * 256 + threadIdx.x;
  if (i >= total) return;
  int m = i / K, k = i - m * K;
  float f = src[(size_t)m * sld + k];
  unsigned short hi = f2bf(f);
  unsigned short lo = f2bf(f - bf2f(hi));
  size_t o = ((size_t)m * K + k) * 3;
  dst[o] = hi; dst[o + 1] = lo; dst[o + 2] = hi;
}
__global__ __launch_bounds__(256) void conv_augW_kernel(
    const float* __restrict__ src, unsigned short* __restrict__ dst,
    int rows, int total, int K, int sld) {
  int i = blockIdx.x * 256 + threadIdx.x;
  if (i >= total) return;
  int n = i / K, k = i - n * K;
  unsigned short hi = 0, lo = 0;
  if (n < rows) {
    float f = src[(size_t)n * sld + k];
    hi = f2bf(f);
    lo = f2bf(f - bf2f(hi));
  }
  size_t o = ((size_t)n * K + k) * 3;
  dst[o] = hi; dst[o + 1] = hi; dst[o + 2] = lo;
}

// ---------------- conv1d(4-tap, causal) + SiLU ----------------
__global__ __launch_bounds__(256) void conv_silu_kernel(
    const float* __restrict__ zxbcdt, const float* __restrict__ conv_w,
    const float* __restrict__ conv_b, float* __restrict__ xBC) {
  int idx = blockIdx.x * 256 + threadIdx.x;
  if (idx >= L * CONVCH) return;
  int l = idx / CONVCH, c = idx - l * CONVCH;
  float acc = conv_b[c];
#pragma unroll
  for (int k = 0; k < 4; ++k) {
    int ls = l - 3 + k;
    if (ls >= 0) acc += zxbcdt[(size_t)ls * INDIM + DINNER + c] * conv_w[c * 4 + k];
  }
  xBC[idx] = acc / (1.f + expf(-acc));
}

// ---------------- dt / logdA ----------------
__global__ __launch_bounds__(256) void dt_kernel(
    const float* __restrict__ zxbcdt, const float* __restrict__ dt_bias,
    const float* __restrict__ A_log, float* __restrict__ dt, float* __restrict__ logdA) {
  int idx = blockIdx.x * 256 + threadIdx.x;
  int l = idx >> 5, h = idx & 31;
  float xv = zxbcdt[(size_t)l * INDIM + (INDIM - MNH) + h] + dt_bias[h];
  float sp = fmaxf(xv, 0.f) + log1pf(expf(-fabsf(xv)));
  dt[idx] = sp;
  logdA[idx] = sp * -expf(A_log[h]);
}

// ---------------- lcd ----------------
__global__ __launch_bounds__(256) void lcd_kernel(
    const float* __restrict__ logdA, float* __restrict__ lcd) {
  int i = blockIdx.x * 256 + threadIdx.x;
  if (i >= NCH * MNH) return;
  int c = i >> 5, h = i & 31;
  float s = 0.f;
  for (int t = 0; t < CHUNK; ++t) {
    s += logdA[(c * CHUNK + t) * MNH + h];
    lcd[(size_t)i * CHUNK + t] = s;
  }
}

// ---------------- G[c][t][s] = C_t . B_s ----------------
__global__ __launch_bounds__(256) void chunk_G_kernel(
    const float* __restrict__ xBC, float* __restrict__ G) {
  int c = blockIdx.x, tid = threadIdx.x;
  __shared__ float BsT[64][68];
  __shared__ float Cs[64][65];
  int t = tid >> 2, q = tid & 3;
  const float* row = xBC + (size_t)(c * 64 + t) * CONVCH + DINNER;
#pragma unroll
  for (int j = 0; j < 16; j += 4) {
    float4 b = *(const float4*)(row + q * 16 + j);
    BsT[q * 16 + j + 0][t] = b.x; BsT[q * 16 + j + 1][t] = b.y;
    BsT[q * 16 + j + 2][t] = b.z; BsT[q * 16 + j + 3][t] = b.w;
    float4 cv = *(const float4*)(row + 64 + q * 16 + j);
    Cs[t][q * 16 + j + 0] = cv.x; Cs[t][q * 16 + j + 1] = cv.y;
    Cs[t][q * 16 + j + 2] = cv.z; Cs[t][q * 16 + j + 3] = cv.w;
  }
  __syncthreads();
  int s0 = q * 16;
  f32x4 g0 = {}, g1 = {}, g2 = {}, g3 = {};
  for (int n = 0; n < 64; ++n) {
    f32x4 cv = splat4(Cs[t][n]);
    g0 += cv * *(const f32x4*)&BsT[n][s0];
    g1 += cv * *(const f32x4*)&BsT[n][s0 + 4];
    g2 += cv * *(const f32x4*)&BsT[n][s0 + 8];
    g3 += cv * *(const f32x4*)&BsT[n][s0 + 12];
  }
  float* gp = G + ((size_t)c * 64 + t) * 64 + s0;
  *(f32x4*)gp = g0; *(f32x4*)(gp + 4) = g1; *(f32x4*)(gp + 8) = g2; *(f32x4*)(gp + 12) = g3;
}

// ---------------- scan pass A ----------------
__global__ __launch_bounds__(256) void scan_local_kernel(
    const float* __restrict__ xBC, const float* __restrict__ dt,
    const float* __restrict__ lcd, float* __restrict__ hstate) {
  int c = blockIdx.x >> 5, h = blockIdx.x & 31;
  int tid = threadIdx.x;
  __shared__ float Bs[64][68];
  __shared__ float xss[64][36];
  __shared__ float w2s[64];
  int t0 = c * CHUNK;
  int t = tid >> 2, q = tid & 3;
  const float* row = xBC + (size_t)(t0 + t) * CONVCH;
#pragma unroll
  for (int j = 0; j < 16; j += 4)
    *(float4*)&Bs[t][q * 16 + j] = *(const float4*)(row + DINNER + q * 16 + j);
  if (q < 2) {
#pragma unroll
    for (int j = 0; j < 16; j += 4)
      *(float4*)&xss[t][q * 16 + j] = *(const float4*)(row + h * 32 + q * 16 + j);
  }
  if (tid < 64) {
    const float* lc = lcd + ((size_t)c * 32 + h) * CHUNK;
    w2s[tid] = expf(lc[63] - lc[tid]) * dt[(t0 + tid) * MNH + h];
  }
  __syncthreads();
  int n = tid >> 2, pg = (tid & 3) * 8;
  f32x4 h0 = {}, h1 = {};
  for (int s = 0; s < 64; ++s) {
    f32x4 wb = splat4(w2s[s] * Bs[s][n]);
    h0 += wb * *(const f32x4*)&xss[s][pg];
    h1 += wb * *(const f32x4*)&xss[s][pg + 4];
  }
  float* hp = hstate + ((size_t)c * 32 + h) * 2048 + n * 32 + pg;
  *(f32x4*)hp = h0; *(f32x4*)(hp + 4) = h1;
}

// ---------------- scan pass B ----------------
__global__ __launch_bounds__(256) void scan_combine_kernel(
    float* __restrict__ hstate, const float* __restrict__ lcd) {
  int i = blockIdx.x * 256 + threadIdx.x;
  int h = i >> 11;
  float H = 0.f;
  for (int c = 0; c < NCH; ++c) {
    float hl = hstate[(size_t)c * 65536 + i];
    hstate[(size_t)c * 65536 + i] = H;
    float P = expf(lcd[((size_t)c * 32 + h) * CHUNK + CHUNK - 1]);
    H = H * P + hl;
  }
}

// ---------------- scan pass C ----------------
__global__ __launch_bounds__(256) void scan_y_kernel(
    const float* __restrict__ xBC, const float* __restrict__ G,
    const float* __restrict__ dt, const float* __restrict__ lcd,
    const float* __restrict__ hstate, float* __restrict__ y) {
  int c = blockIdx.x >> 5, h = blockIdx.x & 31;
  int tid = threadIdx.x;
  __shared__ float Ms[64][65];
  __shared__ float Cs[64][65];
  __shared__ float xss[64][36];
  __shared__ float Hss[64][36];
  __shared__ float lcds[64], dts[64];
  int t0 = c * CHUNK;
  int t = tid >> 2, q = tid & 3;
  const float* row = xBC + (size_t)(t0 + t) * CONVCH;
#pragma unroll
  for (int j = 0; j < 16; j += 4) {
    float4 cv = *(const float4*)(row + DINNER + 64 + q * 16 + j);
    Cs[t][q * 16 + j + 0] = cv.x; Cs[t][q * 16 + j + 1] = cv.y;
    Cs[t][q * 16 + j + 2] = cv.z; Cs[t][q * 16 + j + 3] = cv.w;
  }
  if (q < 2) {
#pragma unroll
    for (int j = 0; j < 16; j += 4)
      *(float4*)&xss[t][q * 16 + j] = *(const float4*)(row + h * 32 + q * 16 + j);
  }
  {
    const float* gp = G + ((size_t)c * 64 + t) * 64 + q * 16;
#pragma unroll
    for (int j = 0; j < 16; j += 4) {
      float4 g = *(const float4*)(gp + j);
      Ms[t][q * 16 + j + 0] = g.x; Ms[t][q * 16 + j + 1] = g.y;
      Ms[t][q * 16 + j + 2] = g.z; Ms[t][q * 16 + j + 3] = g.w;
    }
  }
  {
    const float* hp = hstate + ((size_t)c * 32 + h) * 2048 + tid * 8;
    int n = tid >> 2, p0 = (tid & 3) * 8;
    *(float4*)&Hss[n][p0]     = *(const float4*)hp;
    *(float4*)&Hss[n][p0 + 4] = *(const float4*)(hp + 4);
  }
  if (tid < 64) {
    lcds[tid] = lcd[((size_t)c * 32 + h) * CHUNK + tid];
    dts[tid]  = dt[(t0 + tid) * MNH + h];
  }
  __syncthreads();
  {
    int s0 = q * 16;
#pragma unroll
    for (int j = 0; j < 16; ++j) {
      int s = s0 + j;
      float m = (s <= t) ? expf(lcds[t] - lcds[s]) * dts[s] * Ms[t][s] : 0.f;
      Ms[t][s] = m;
    }
  }
  __syncthreads();
  int pg = q * 8;
  f32x4 y0 = {}, y1 = {}, a0 = {}, a1 = {};
  for (int s = 0; s < 64; ++s) {
    f32x4 m = splat4(Ms[t][s]);
    y0 += m * *(const f32x4*)&xss[s][pg];
    y1 += m * *(const f32x4*)&xss[s][pg + 4];
  }
  for (int n = 0; n < 64; ++n) {
    f32x4 cn = splat4(Cs[t][n]);
    a0 += cn * *(const f32x4*)&Hss[n][pg];
    a1 += cn * *(const f32x4*)&Hss[n][pg + 4];
  }
  f32x4 cd = splat4(expf(lcds[t]));
  y0 += cd * a0; y1 += cd * a1;
  float* yp = y + (size_t)(t0 + t) * DINNER + h * 32 + pg;
  *(f32x4*)yp = y0; *(f32x4*)(yp + 4) = y1;
}

// ---------------- gate + RMSNorm ----------------
__global__ __launch_bounds__(256) void gatenorm_kernel(
    const float* __restrict__ y_ssm, const float* __restrict__ xBC,
    const float* __restrict__ zxbcdt, const float* __restrict__ Dv,
    const float* __restrict__ norm_w, float* __restrict__ out) {
  int l = blockIdx.x, tid = threadIdx.x;
  float vals[4];
  float ss = 0.f;
#pragma unroll
  for (int i = 0; i < 4; ++i) {
    int d = tid + i * 256;
    int h = d >> 5;
    float v = y_ssm[(size_t)l * DINNER + d] + Dv[h] * xBC[(size_t)l * CONVCH + d];
    float z = zxbcdt[(size_t)l * INDIM + d];
    v *= z / (1.f + expf(-z));
    vals[i] = v;
    ss += v * v;
  }
#pragma unroll
  for (int off = 32; off > 0; off >>= 1) ss += __shfl_xor(ss, off);
  __shared__ float sred[4];
  if ((tid & 63) == 0) sred[tid >> 6] = ss;
  __syncthreads();
  float tot = sred[0] + sred[1] + sred[2] + sred[3];
  float scale = rsqrtf(tot * (1.f / 1024.f) + 1e-5f);
#pragma unroll
  for (int i = 0; i < 4; ++i) {
    int d = tid + i * 256;
    out[(size_t)l * DINNER + d] = vals[i] * scale * norm_w[d];
  }
}

// ---------------- per-row top-64 radix select ----------------
__global__ __launch_bounds__(256) void topk_kernel(
    const float* __restrict__ scores, int* __restrict__ out_idx) {
  int l = blockIdx.x, tid = threadIdx.x;
  if (l < 64) {
    if (tid < 64) out_idx[l * 64 + tid] = tid;
    return;
  }
  int n = l + 1;
  const float* row = scores + (size_t)l * L;
  __shared__ int hist[256];
  __shared__ unsigned sel_prefix;
  __shared__ int sel_remaining;
  __shared__ int cnt_g, cnt_e;
  __shared__ int eq_list[128];
  if (tid == 0) { cnt_g = 0; cnt_e = 0; }
  unsigned prefix = 0;
  int remaining = 64;
  for (int pass = 0; pass < 4; ++pass) {
    int shift = 24 - 8 * pass;
    unsigned himask = (pass == 0) ? 0u : (0xFFFFFFFFu << (shift + 8));
    hist[tid] = 0;
    __syncthreads();
    for (int j = tid; j < n; j += 256) {
      unsigned u = __float_as_uint(row[j]);
      unsigned key = (u & 0x80000000u) ? ~u : (u | 0x80000000u);
      if (((key ^ prefix) & himask) == 0)
        atomicAdd(&hist[(key >> shift) & 255], 1);
    }
    __syncthreads();
    if (tid == 0) {
      int cum = 0, b = 255;
      for (; b >= 0; --b) {
        cum += hist[b];
        if (cum >= remaining) break;
      }
      sel_prefix = prefix | ((unsigned)b << shift);
      sel_remaining = remaining - (cum - hist[b]);
    }
    __syncthreads();
    prefix = sel_prefix;
    remaining = sel_remaining;
    __syncthreads();
  }
  unsigned T = prefix;
  for (int j = tid; j < n; j += 256) {
    unsigned u = __float_as_uint(row[j]);
    unsigned key = (u & 0x80000000u) ? ~u : (u | 0x80000000u);
    if (key > T) {
      int p = atomicAdd(&cnt_g, 1);
      out_idx[l * 64 + p] = j;
    } else if (key == T) {
      int p = atomicAdd(&cnt_e, 1);
      if (p < 128) eq_list[p] = j;
    }
  }
  __syncthreads();
  if (tid == 0) {
    int G = cnt_g;
    int E = remaining;
    int m = cnt_e < 128 ? cnt_e : 128;
    for (int e = 0; e < E; ++e) {
      int best = 0, bj = 0x7fffffff;
      for (int i = 0; i < m; ++i)
        if (eq_list[i] < bj) { bj = eq_list[i]; best = i; }
      out_idx[l * 64 + G + e] = bj;
      eq_list[best] = 0x7fffffff;
    }
  }
}

// ---------------- RoPE + pack q_final/k_final (fused-buffer strides) ----------------
// qbuf row: [q_cont(1024) | q_rope_lin(512)], stride 1536
// k_rope_lin: c3 + l*384 + 256
__global__ __launch_bounds__(128) void rope_pack_kernel(
    const float* __restrict__ qbuf, const float* __restrict__ kv,
    const float* __restrict__ c3,
    float* __restrict__ q_final, float* __restrict__ k_final) {
  int l = blockIdx.x, tid = threadIdx.x;
  __shared__ float s_s[16], s_c[16];
  if (tid < 16) {
    float inv = powf(10000.f, -(float)tid / 16.f);
    float ang = (float)l * inv;
    s_s[tid] = sinf(ang);
    s_c[tid] = cosf(ang);
  }
  __syncthreads();
  const float* qrow = qbuf + (size_t)l * 1536;
  const float* krow = c3 + (size_t)l * 384 + 256;
  for (int e = tid; e < NH * 96; e += 128) {
    int hh = e / 96, d = e - hh * 96;
    float qv, kvv;
    if (d < 64) {
      qv  = qrow[hh * 64 + d];
      kvv = kv[(size_t)l * 2048 + hh * 64 + d];
    } else {
      int r = d - 64;
      if (r < 16) {
        float q1 = qrow[1024 + hh * 32 + r];
        float q2 = qrow[1024 + hh * 32 + 16 + r];
        qv = q1 * s_c[r] - q2 * s_s[r];
        float k1 = krow[r];
        float k2 = krow[16 + r];
        kvv = k1 * s_c[r] - k2 * s_s[r];
      } else {
        int rr = r - 16;
        float q1 = qrow[1024 + hh * 32 + rr];
        float q2 = qrow[1024 + hh * 32 + 16 + rr];
        qv = q1 * s_s[rr] + q2 * s_c[rr];
        float k1 = krow[rr];
        float k2 = krow[16 + rr];
        kvv = k1 * s_s[rr] + k2 * s_c[rr];
      }
    }
    q_final[(size_t)l * 1536 + e] = qv;
    k_final[(size_t)l * 1536 + e] = kvv;
  }
}

// ---------------- sparse attention ----------------
__global__ __launch_bounds__(256) void attn_kernel(
    const float* __restrict__ q_final, const float* __restrict__ k_final,
    const float* __restrict__ kv, const int* __restrict__ idx,
    unsigned short* __restrict__ attn_aug) {
  int w = blockIdx.x * 4 + (threadIdx.x >> 6);
  int lane = threadIdx.x & 63;
  int l = w >> 4, h = w & 15;
  int ik = idx[l * 64 + lane];
  const float4* qp = (const float4*)(q_final + (size_t)l * 1536 + h * 96);
  const float4* kp = (const float4*)(k_final + (size_t)ik * 1536 + h * 96);
  float dot = 0.f;
#pragma unroll
  for (int j = 0; j < 24; ++j) {
    float4 q4 = qp[j], k4 = kp[j];
    dot += q4.x * k4.x + q4.y * k4.y + q4.z * k4.z + q4.w * k4.w;
  }
  float logit = dot * 0.10206207261596575f;
  float m = logit;
#pragma unroll
  for (int off = 32; off > 0; off >>= 1) m = fmaxf(m, __shfl_xor(m, off));
  float e = expf(logit - m);
  float ssum = e;
#pragma unroll
  for (int off = 32; off > 0; off >>= 1) ssum += __shfl_xor(ssum, off);
  float wgt = e / ssum;
  float acc = 0.f;
  const float* vbase = kv + 1024 + h * 64 + lane;
  for (int k = 0; k < 64; ++k) {
    float wk = __shfl(wgt, k);
    int kk = __shfl(ik, k);
    acc += wk * vbase[(size_t)kk * 2048];
  }
  unsigned short hi = f2bf(acc);
  unsigned short lo = f2bf(acc - bf2f(hi));
  size_t o = ((size_t)l * 1024 + h * 64 + lane) * 3;
  attn_aug[o] = hi; attn_aug[o + 1] = lo; attn_aug[o + 2] = hi;
}

// ---------------- host ----------------
extern "C" void kernel_launch(void* const* d_in, const int* in_sizes, int n_in,
                              void* d_out, int out_size, void* d_ws, size_t ws_size,
                              hipStream_t stream) {
  const float* x          = (const float*)d_in[0];
  const float* idx_in_w   = (const float*)d_in[1];
  const float* idx_conv_w = (const float*)d_in[2];
  const float* idx_conv_b = (const float*)d_in[3];
  const float* idx_dt_b   = (const float*)d_in[4];
  const float* idx_A_log  = (const float*)d_in[5];
  const float* idx_D      = (const float*)d_in[6];
  const float* idx_norm_w = (const float*)d_in[7];
  const float* idx_out_w  = (const float*)d_in[8];
  const float* idx_q_w    = (const float*)d_in[9];
  const float* idx_k_w    = (const float*)d_in[10];
  const float* q_down_w   = (const float*)d_in[11];
  const float* q_up_w     = (const float*)d_in[12];
  const float* q_rope_w   = (const float*)d_in[13];
  const float* kv_down_w  = (const float*)d_in[14];
  const float* kv_up_w    = (const float*)d_in[15];
  const float* k_rope_w   = (const float*)d_in[16];
  const float* out_w      = (const float*)d_in[17];
  float* out = (float*)d_out;

  // ---- workspace arena (float slots) ----
  float* p = (float*)d_ws;
  float* segA = p; p += 4521984;  // zxbcdt | scores | qbuf[2048x1536]
  float* segB = p; p += 2359296;  // xBC | {q_idx@0, k_idx@131072, c3@262144}
  float* dtb = p; p += 65536;
  float* logdA = p; p += 65536;
  float* lcdb = p; p += 65536;
  int*   idxb = (int*)p; p += 131072;
  float* segD = p; p += 4194304;  // y_ssm+hstate | kvb
  float* segE = p; p += 3145728;  // x_aug | attn_aug
  float* segG = p; p += 3145728;  // y_norm | q_final
  float* segH = p; p += 3145728;  // {out_w_T, qwpad, Wq} | k_final
  unsigned short* w_3down_aug = (unsigned short*)p; p += 589824;  // 384x1024x3
  unsigned short* w_qups_aug  = (unsigned short*)p; p += 294912;  // 1536x128x3
  unsigned short* w_kvup_aug  = (unsigned short*)p; p += 393216;  // 2048x128x3
  unsigned short* c_q_aug     = (unsigned short*)p; p += 393216;
  unsigned short* c_kv_aug    = (unsigned short*)p; p += 393216;
  unsigned short* w_outp_aug  = (unsigned short*)p; p += 1572864; // 1024x1024x3
  float* Gbuf = p; p += 131072;

  float* zxbcdt = segA;
  float* scores = segA;
  float* qbuf   = segA;                       // after topk (scores dead)
  float* xBC    = segB;
  float* q_idx  = segB;                       // after gatenorm (xBC dead)
  float* k_idx  = segB + 131072;
  float* c3     = segB + 262144;              // fused down-proj out [2048x384]
  float* y_ssm  = segD;
  float* hstate = segD + 2097152;
  float* kvb    = segD;
  unsigned short* x_aug    = (unsigned short*)segE;
  unsigned short* attn_aug = (unsigned short*)segE;
  float* y_norm  = segG;
  float* q_final = segG;
  float* out_w_T = segH;                      // 1024x1024
  float* qwpad   = segH + 1048576;            // 128x1024 (zero-padded idx_q_w)
  float* Wq      = segH + 1179648;            // 128x1024 folded weight
  float* k_final = segH;                      // after q_idx gemm (Wq dead)

  dim3 blk(256);
  auto cdiv = [](int a, int b) { return (a + b - 1) / b; };
  auto gemmf3 = [&](const float* A, const float* W, float* C, int M, int N, int K, int S) {
    dim3 grid(cdiv(N, 128), M / 128, S);
    hipLaunchKernelGGL(gemm_f32_v3, grid, blk, 0, stream, A, W, C, M, N, K);
  };
  auto gemmb = [&](const unsigned short* A, const unsigned short* W, float* C,
                   int M, int N, int K, int lda, int ldb, int ldc, int S) {
    dim3 grid(N / 128, M / 128, S);
    hipLaunchKernelGGL(gemm_bf16_kernel, grid, blk, 0, stream, A, W, C, M, N, K, lda, ldb, ldc);
  };
  auto caugA = [&](const float* s, unsigned short* d, int total, int K, int sld) {
    hipLaunchKernelGGL(conv_augA_kernel, dim3(cdiv(total, 256)), blk, 0, stream, s, d, total, K, sld);
  };
  auto caugW = [&](const float* s, unsigned short* d, int rows, int total, int K, int sld) {
    hipLaunchKernelGGL(conv_augW_kernel, dim3(cdiv(total, 256)), blk, 0, stream, s, d, rows, total, K, sld);
  };

  // ---- weight precomputes ----
  // Wq' = idx_q_w @ idx_out_w  (q_idx = y_norm @ Wq'^T): kills the 2048x1024x1024 out-proj
  hipLaunchKernelGGL(transpose1024_kernel, dim3(1024), blk, 0, stream, idx_out_w, out_w_T);
  hipMemsetAsync(qwpad, 0, 131072 * 4, stream);
  hipMemcpyAsync(qwpad, idx_q_w, (size_t)64 * 1024 * 4, hipMemcpyDeviceToDevice, stream);
  hipMemsetAsync(Wq, 0, 131072 * 4, stream);
  gemmf3(qwpad, out_w_T, Wq, 128, 1024, 1024, 8);
  // value-path aug weights (fused blocks)
  caugA(x, x_aug, 2048 * 1024, 1024, 1024);
  caugW(q_down_w,  w_3down_aug,                    128, 128 * 1024, 1024, 1024);
  caugW(kv_down_w, w_3down_aug + 128 * 1024 * 3,   128, 128 * 1024, 1024, 1024);
  caugW(k_rope_w,  w_3down_aug + 256 * 1024 * 3,    32, 128 * 1024, 1024, 1024);
  caugW(q_up_w,    w_qups_aug,                    1024, 1024 * 128, 128, 128);
  caugW(q_rope_w,  w_qups_aug + 1024 * 128 * 3,    512, 512 * 128, 128, 128);
  caugW(kv_up_w,   w_kvup_aug, 2048, 2048 * 128, 128, 128);
  caugW(out_w,     w_outp_aug, 1024, 1024 * 1024, 1024, 1024);

  // ---- mamba branch (fp32 index-critical) ----
  hipMemsetAsync(zxbcdt, 0, (size_t)L * INDIM * 4, stream);
  gemmf3(x, idx_in_w, zxbcdt, 2048, INDIM, 1024, 2);
  hipLaunchKernelGGL(conv_silu_kernel, dim3(cdiv(L * CONVCH, 256)), blk, 0, stream,
                     zxbcdt, idx_conv_w, idx_conv_b, xBC);
  hipLaunchKernelGGL(dt_kernel, dim3(L * MNH / 256), blk, 0, stream,
                     zxbcdt, idx_dt_b, idx_A_log, dtb, logdA);
  hipLaunchKernelGGL(lcd_kernel, dim3(4), blk, 0, stream, logdA, lcdb);
  hipLaunchKernelGGL(chunk_G_kernel, dim3(NCH), blk, 0, stream, xBC, Gbuf);
  hipLaunchKernelGGL(scan_local_kernel, dim3(NCH * MNH), blk, 0, stream,
                     xBC, dtb, lcdb, hstate);
  hipLaunchKernelGGL(scan_combine_kernel, dim3(256), blk, 0, stream, hstate, lcdb);
  hipLaunchKernelGGL(scan_y_kernel, dim3(NCH * MNH), blk, 0, stream,
                     xBC, Gbuf, dtb, lcdb, hstate, y_ssm);
  hipLaunchKernelGGL(gatenorm_kernel, dim3(L), blk, 0, stream,
                     y_ssm, xBC, zxbcdt, idx_D, idx_norm_w, y_norm);

  // ---- index scores + topk (out-proj folded into Wq) ----
  hipMemsetAsync(q_idx, 0, 131072 * 4, stream);
  hipMemsetAsync(k_idx, 0, 131072 * 4, stream);
  gemmf3(y_norm, Wq, q_idx, 2048, 64, 1024, 16);
  gemmf3(x, idx_k_w, k_idx, 2048, 64, 1024, 16);
  gemmf3(q_idx, k_idx, scores, 2048, 2048, 64, 1);
  hipLaunchKernelGGL(topk_kernel, dim3(L), blk, 0, stream, scores, idxb);

  // ---- attention value path (aug split-bf16 MFMA, fused GEMMs) ----
  hipMemsetAsync(c3, 0, 786432 * 4, stream);
  gemmb(x_aug, w_3down_aug, c3, 2048, 384, 3072, 3072, 3072, 384, 8);
  caugA(c3, c_q_aug, 2048 * 128, 128, 384);
  caugA(c3 + 128, c_kv_aug, 2048 * 128, 128, 384);
  gemmb(c_q_aug, w_qups_aug, qbuf, 2048, 1536, 384, 384, 384, 1536, 1);
  gemmb(c_kv_aug, w_kvup_aug, kvb, 2048, 2048, 384, 384, 384, 2048, 1);
  hipLaunchKernelGGL(rope_pack_kernel, dim3(L), dim3(128), 0, stream,
                     qbuf, kvb, c3, q_final, k_final);

  // ---- sparse attention + output projection ----
  hipLaunchKernelGGL(attn_kernel, dim3(L * NH / 4), blk, 0, stream,
                     q_final, k_final, kvb, idxb, attn_aug);
  hipMemsetAsync(out, 0, (size_t)out_size * 4, stream);
  gemmb(attn_aug, w_outp_aug, out, 2048, 1024, 3072, 3072, 3072, 1024, 2);
}

// Round 13
// 824.359 us; speedup vs baseline: 1.4830x; 1.0415x over previous
//
#include <hip/hip_runtime.h>
#include <math.h>

// ---------------- constants ----------------
constexpr int L      = 2048;
constexpr int NH     = 16;
constexpr int DINNER = 1024;
constexpr int MNH    = 32;
constexpr int CONVCH = 1152;
constexpr int INDIMP = 2304;   // padded stride for zxbcdt (2208 -> 2304, N%128)
constexpr int CHUNK  = 64;
constexpr int NCH    = 32;

using bf16x8 = __attribute__((ext_vector_type(8))) short;
using f32x4  = __attribute__((ext_vector_type(4))) float;

__device__ __forceinline__ f32x4 splat4(float x) { return (f32x4){x, x, x, x}; }

__device__ __forceinline__ unsigned short f2bf(float f) {
  unsigned u = __float_as_uint(f);
  return (unsigned short)((u + 0x7fffu + ((u >> 16) & 1u)) >> 16);
}
__device__ __forceinline__ float bf2f(unsigned short h) {
  return __uint_as_float((unsigned)h << 16);
}

// ---------------- fp32 GEMM v3 (small index-critical shapes) ----------------
__global__ __launch_bounds__(256) void gemm_f32_v3(
    const float* __restrict__ A, const float* __restrict__ W,
    float* __restrict__ C, int M, int N, int K) {
  __shared__ float As[16][132];
  __shared__ float Ws[16][132];
  int tid = threadIdx.x;
  int bm = blockIdx.y * 128, bn = blockIdx.x * 128;
  int kper = K / gridDim.z;
  int kb = blockIdx.z * kper, ke = kb + kper;
  int lr = tid >> 1;
  int lh = (tid & 1) * 8;
  int tx = tid & 15, ty = tid >> 4;
  bool wok = (bn + lr < N);
  const float* arow = A + (size_t)(bm + lr) * K + lh;
  const float* wrow = W + (size_t)(bn + lr) * K + lh;
  float4 a0, a1, w0, w1;
  auto gload = [&](int k0) {
    a0 = *(const float4*)(arow + k0);
    a1 = *(const float4*)(arow + k0 + 4);
    w0 = make_float4(0.f, 0.f, 0.f, 0.f); w1 = w0;
    if (wok) {
      w0 = *(const float4*)(wrow + k0);
      w1 = *(const float4*)(wrow + k0 + 4);
    }
  };
  f32x4 acc0[8] = {}, acc1[8] = {};
  gload(kb);
  for (int k0 = kb; k0 < ke; k0 += 16) {
    __syncthreads();
    As[lh+0][lr]=a0.x; As[lh+1][lr]=a0.y; As[lh+2][lr]=a0.z; As[lh+3][lr]=a0.w;
    As[lh+4][lr]=a1.x; As[lh+5][lr]=a1.y; As[lh+6][lr]=a1.z; As[lh+7][lr]=a1.w;
    Ws[lh+0][lr]=w0.x; Ws[lh+1][lr]=w0.y; Ws[lh+2][lr]=w0.z; Ws[lh+3][lr]=w0.w;
    Ws[lh+4][lr]=w1.x; Ws[lh+5][lr]=w1.y; Ws[lh+6][lr]=w1.z; Ws[lh+7][lr]=w1.w;
    __syncthreads();
    if (k0 + 16 < ke) gload(k0 + 16);
#pragma unroll
    for (int kk = 0; kk < 16; ++kk) {
      f32x4 b0 = *(const f32x4*)&Ws[kk][tx * 4];
      f32x4 b1 = *(const f32x4*)&Ws[kk][64 + tx * 4];
      f32x4 al = *(const f32x4*)&As[kk][ty * 8];
      f32x4 ah = *(const f32x4*)&As[kk][ty * 8 + 4];
#pragma unroll
      for (int i = 0; i < 4; ++i) {
        acc0[i]     += splat4(al[i]) * b0;
        acc1[i]     += splat4(al[i]) * b1;
        acc0[i + 4] += splat4(ah[i]) * b0;
        acc1[i + 4] += splat4(ah[i]) * b1;
      }
    }
  }
  bool single = (gridDim.z == 1);
#pragma unroll
  for (int i = 0; i < 8; ++i) {
    int row = bm + ty * 8 + i;
    float* crow = C + (size_t)row * N;
    int c0 = bn + tx * 4, c1 = bn + 64 + tx * 4;
    if (c0 + 3 < N) {
      if (single) *(f32x4*)(crow + c0) = acc0[i];
      else {
        atomicAdd(crow + c0 + 0, acc0[i][0]); atomicAdd(crow + c0 + 1, acc0[i][1]);
        atomicAdd(crow + c0 + 2, acc0[i][2]); atomicAdd(crow + c0 + 3, acc0[i][3]);
      }
    }
    if (c1 + 3 < N) {
      if (single) *(f32x4*)(crow + c1) = acc1[i];
      else {
        atomicAdd(crow + c1 + 0, acc1[i][0]); atomicAdd(crow + c1 + 1, acc1[i][1]);
        atomicAdd(crow + c1 + 2, acc1[i][2]); atomicAdd(crow + c1 + 3, acc1[i][3]);
      }
    }
  }
}

// ---------------- 1024x1024 transpose ----------------
__global__ __launch_bounds__(256) void transpose1024_kernel(
    const float* __restrict__ src, float* __restrict__ dst) {
  __shared__ float t[32][33];
  int bx = blockIdx.x & 31, by = blockIdx.x >> 5;
  int tx = threadIdx.x & 31, ty8 = threadIdx.x >> 5;
  for (int r = ty8; r < 32; r += 8)
    t[r][tx] = src[(size_t)(by * 32 + r) * 1024 + bx * 32 + tx];
  __syncthreads();
  for (int r = ty8; r < 32; r += 8)
    dst[(size_t)(bx * 32 + r) * 1024 + by * 32 + tx] = t[tx][r];
}

// ---------------- bf16 MFMA GEMM ----------------
__global__ __launch_bounds__(256) void gemm_bf16_kernel(
    const unsigned short* __restrict__ A, const unsigned short* __restrict__ W,
    float* __restrict__ C, int M, int N, int K, int lda, int ldb, int ldc) {
  __shared__ unsigned short As[128 * 64];
  __shared__ unsigned short Ws[128 * 64];
  int tid = threadIdx.x;
  int bm = blockIdx.y * 128, bn = blockIdx.x * 128;
  int kper = K / gridDim.z;
  int k_begin = blockIdx.z * kper;
  int k_end = k_begin + kper;
  int wv = tid >> 6, lane = tid & 63;
  int wrow = (wv >> 1) * 64, wcol = (wv & 1) * 64;
  int lrow = lane & 15, quad = lane >> 4;

  f32x4 acc[4][4] = {};

  for (int k0 = k_begin; k0 < k_end; k0 += 64) {
    __syncthreads();
#pragma unroll
    for (int it = 0; it < 4; ++it) {
      int s = it * 256 + tid;
      int r = s >> 3;
      int q = (s & 7) ^ (r & 7);
      const unsigned short* ga = A + (size_t)(bm + r) * lda + k0 + q * 8;
      const unsigned short* gw = W + (size_t)(bn + r) * ldb + k0 + q * 8;
      __builtin_amdgcn_global_load_lds((const __attribute__((address_space(1))) void*)ga,
                                       (__attribute__((address_space(3))) void*)&As[s * 8], 16, 0, 0);
      __builtin_amdgcn_global_load_lds((const __attribute__((address_space(1))) void*)gw,
                                       (__attribute__((address_space(3))) void*)&Ws[s * 8], 16, 0, 0);
    }
    __syncthreads();
#pragma unroll
    for (int ks = 0; ks < 2; ++ks) {
      bf16x8 af[4], wf[4];
#pragma unroll
      for (int i = 0; i < 4; ++i) {
        int ra = wrow + i * 16 + lrow;
        int qa = (ks * 4 + quad) ^ (ra & 7);
        af[i] = *(const bf16x8*)&As[(ra * 8 + qa) * 8];
        int rw = wcol + i * 16 + lrow;
        int qw = (ks * 4 + quad) ^ (rw & 7);
        wf[i] = *(const bf16x8*)&Ws[(rw * 8 + qw) * 8];
      }
#pragma unroll
      for (int i = 0; i < 4; ++i)
#pragma unroll
        for (int j = 0; j < 4; ++j)
          acc[i][j] = __builtin_amdgcn_mfma_f32_16x16x32_bf16(af[i], wf[j], acc[i][j], 0, 0, 0);
    }
  }
  bool single = (gridDim.z == 1);
#pragma unroll
  for (int i = 0; i < 4; ++i)
#pragma unroll
    for (int j = 0; j < 4; ++j)
#pragma unroll
      for (int r = 0; r < 4; ++r) {
        int row = bm + wrow + i * 16 + quad * 4 + r;
        int col = bn + wcol + j * 16 + lrow;
        float v = acc[i][j][r];
        if (single) C[(size_t)row * ldc + col] = v;
        else atomicAdd(&C[(size_t)row * ldc + col], v);
      }
}

// ---------------- conversions ----------------
// 3-slot aug (value path): A=[h,l,h], W=[h,h,l]
__global__ __launch_bounds__(256) void conv_augA_kernel(
    const float* __restrict__ src, unsigned short* __restrict__ dst,
    int total, int K, int sld) {
  int i = blockIdx.x * 256 + threadIdx.x;
  if (i >= total) return;
  int m = i / K, k = i - m * K;
  float f = src[(size_t)m * sld + k];
  unsigned short hi = f2bf(f);
  unsigned short lo = f2bf(f - bf2f(hi));
  size_t o = ((size_t)m * K + k) * 3;
  dst[o] = hi; dst[o + 1] = lo; dst[o + 2] = hi;
}
__global__ __launch_bounds__(256) void conv_augW_kernel(
    const float* __restrict__ src, unsigned short* __restrict__ dst,
    int rows, int total, int K, int sld) {
  int i = blockIdx.x * 256 + threadIdx.x;
  if (i >= total) return;
  int n = i / K, k = i - n * K;
  unsigned short hi = 0, lo = 0;
  if (n < rows) {
    float f = src[(size_t)n * sld + k];
    hi = f2bf(f);
    lo = f2bf(f - bf2f(hi));
  }
  size_t o = ((size_t)n * K + k) * 3;
  dst[o] = hi; dst[o + 1] = hi; dst[o + 2] = lo;
}
// 6-slot triple split (index path): A=[h,m,l,h,m,h], W=[h,h,h,m,m,l]
// kept: hh+mh+lh+hm+mm+hl; dropped ml/lm/ll ~2^-27.
__global__ __launch_bounds__(256) void conv_tripA_kernel(
    const float* __restrict__ src, unsigned short* __restrict__ dst,
    int total, int K) {
  int i = blockIdx.x * 256 + threadIdx.x;
  if (i >= total) return;
  float f = src[i];
  unsigned short h = f2bf(f);
  float r1 = f - bf2f(h);
  unsigned short m = f2bf(r1);
  unsigned short l = f2bf(r1 - bf2f(m));
  size_t o = (size_t)i * 6;
  dst[o] = h; dst[o + 1] = m; dst[o + 2] = l;
  dst[o + 3] = h; dst[o + 4] = m; dst[o + 5] = h;
}
__global__ __launch_bounds__(256) void conv_tripW_kernel(
    const float* __restrict__ src, unsigned short* __restrict__ dst,
    int rows, int total, int K) {
  int i = blockIdx.x * 256 + threadIdx.x;
  if (i >= total) return;
  int n = i / K, k = i - n * K;
  unsigned short h = 0, m = 0, l = 0;
  if (n < rows) {
    float f = src[(size_t)n * K + k];
    h = f2bf(f);
    float r1 = f - bf2f(h);
    m = f2bf(r1);
    l = f2bf(r1 - bf2f(m));
  }
  size_t o = (size_t)i * 6;
  dst[o] = h; dst[o + 1] = h; dst[o + 2] = h;
  dst[o + 3] = m; dst[o + 4] = m; dst[o + 5] = l;
}

// ---------------- conv1d(4-tap, causal) + SiLU ----------------
__global__ __launch_bounds__(256) void conv_silu_kernel(
    const float* __restrict__ zxbcdt, const float* __restrict__ conv_w,
    const float* __restrict__ conv_b, float* __restrict__ xBC) {
  int idx = blockIdx.x * 256 + threadIdx.x;
  if (idx >= L * CONVCH) return;
  int l = idx / CONVCH, c = idx - l * CONVCH;
  float acc = conv_b[c];
#pragma unroll
  for (int k = 0; k < 4; ++k) {
    int ls = l - 3 + k;
    if (ls >= 0) acc += zxbcdt[(size_t)ls * INDIMP + DINNER + c] * conv_w[c * 4 + k];
  }
  xBC[idx] = acc / (1.f + expf(-acc));
}

// ---------------- dt / logdA (dt cols at 2176..2207) ----------------
__global__ __launch_bounds__(256) void dt_kernel(
    const float* __restrict__ zxbcdt, const float* __restrict__ dt_bias,
    const float* __restrict__ A_log, float* __restrict__ dt, float* __restrict__ logdA) {
  int idx = blockIdx.x * 256 + threadIdx.x;
  int l = idx >> 5, h = idx & 31;
  float xv = zxbcdt[(size_t)l * INDIMP + 2176 + h] + dt_bias[h];
  float sp = fmaxf(xv, 0.f) + log1pf(expf(-fabsf(xv)));
  dt[idx] = sp;
  logdA[idx] = sp * -expf(A_log[h]);
}

// ---------------- lcd ----------------
__global__ __launch_bounds__(256) void lcd_kernel(
    const float* __restrict__ logdA, float* __restrict__ lcd) {
  int i = blockIdx.x * 256 + threadIdx.x;
  if (i >= NCH * MNH) return;
  int c = i >> 5, h = i & 31;
  float s = 0.f;
  for (int t = 0; t < CHUNK; ++t) {
    s += logdA[(c * CHUNK + t) * MNH + h];
    lcd[(size_t)i * CHUNK + t] = s;
  }
}

// ---------------- G[c][t][s] = C_t . B_s ----------------
__global__ __launch_bounds__(256) void chunk_G_kernel(
    const float* __restrict__ xBC, float* __restrict__ G) {
  int c = blockIdx.x, tid = threadIdx.x;
  __shared__ float BsT[64][68];
  __shared__ float Cs[64][65];
  int t = tid >> 2, q = tid & 3;
  const float* row = xBC + (size_t)(c * 64 + t) * CONVCH + DINNER;
#pragma unroll
  for (int j = 0; j < 16; j += 4) {
    float4 b = *(const float4*)(row + q * 16 + j);
    BsT[q * 16 + j + 0][t] = b.x; BsT[q * 16 + j + 1][t] = b.y;
    BsT[q * 16 + j + 2][t] = b.z; BsT[q * 16 + j + 3][t] = b.w;
    float4 cv = *(const float4*)(row + 64 + q * 16 + j);
    Cs[t][q * 16 + j + 0] = cv.x; Cs[t][q * 16 + j + 1] = cv.y;
    Cs[t][q * 16 + j + 2] = cv.z; Cs[t][q * 16 + j + 3] = cv.w;
  }
  __syncthreads();
  int s0 = q * 16;
  f32x4 g0 = {}, g1 = {}, g2 = {}, g3 = {};
  for (int n = 0; n < 64; ++n) {
    f32x4 cv = splat4(Cs[t][n]);
    g0 += cv * *(const f32x4*)&BsT[n][s0];
    g1 += cv * *(const f32x4*)&BsT[n][s0 + 4];
    g2 += cv * *(const f32x4*)&BsT[n][s0 + 8];
    g3 += cv * *(const f32x4*)&BsT[n][s0 + 12];
  }
  float* gp = G + ((size_t)c * 64 + t) * 64 + s0;
  *(f32x4*)gp = g0; *(f32x4*)(gp + 4) = g1; *(f32x4*)(gp + 8) = g2; *(f32x4*)(gp + 12) = g3;
}

// ---------------- scan pass A ----------------
__global__ __launch_bounds__(256) void scan_local_kernel(
    const float* __restrict__ xBC, const float* __restrict__ dt,
    const float* __restrict__ lcd, float* __restrict__ hstate) {
  int c = blockIdx.x >> 5, h = blockIdx.x & 31;
  int tid = threadIdx.x;
  __shared__ float Bs[64][68];
  __shared__ float xss[64][36];
  __shared__ float w2s[64];
  int t0 = c * CHUNK;
  int t = tid >> 2, q = tid & 3;
  const float* row = xBC + (size_t)(t0 + t) * CONVCH;
#pragma unroll
  for (int j = 0; j < 16; j += 4)
    *(float4*)&Bs[t][q * 16 + j] = *(const float4*)(row + DINNER + q * 16 + j);
  if (q < 2) {
#pragma unroll
    for (int j = 0; j < 16; j += 4)
      *(float4*)&xss[t][q * 16 + j] = *(const float4*)(row + h * 32 + q * 16 + j);
  }
  if (tid < 64) {
    const float* lc = lcd + ((size_t)c * 32 + h) * CHUNK;
    w2s[tid] = expf(lc[63] - lc[tid]) * dt[(t0 + tid) * MNH + h];
  }
  __syncthreads();
  int n = tid >> 2, pg = (tid & 3) * 8;
  f32x4 h0 = {}, h1 = {};
  for (int s = 0; s < 64; ++s) {
    f32x4 wb = splat4(w2s[s] * Bs[s][n]);
    h0 += wb * *(const f32x4*)&xss[s][pg];
    h1 += wb * *(const f32x4*)&xss[s][pg + 4];
  }
  float* hp = hstate + ((size_t)c * 32 + h) * 2048 + n * 32 + pg;
  *(f32x4*)hp = h0; *(f32x4*)(hp + 4) = h1;
}

// ---------------- scan pass B ----------------
__global__ __launch_bounds__(256) void scan_combine_kernel(
    float* __restrict__ hstate, const float* __restrict__ lcd) {
  int i = blockIdx.x * 256 + threadIdx.x;
  int h = i >> 11;
  float H = 0.f;
  for (int c = 0; c < NCH; ++c) {
    float hl = hstate[(size_t)c * 65536 + i];
    hstate[(size_t)c * 65536 + i] = H;
    float P = expf(lcd[((size_t)c * 32 + h) * CHUNK + CHUNK - 1]);
    H = H * P + hl;
  }
}

// ---------------- scan pass C ----------------
__global__ __launch_bounds__(256) void scan_y_kernel(
    const float* __restrict__ xBC, const float* __restrict__ G,
    const float* __restrict__ dt, const float* __restrict__ lcd,
    const float* __restrict__ hstate, float* __restrict__ y) {
  int c = blockIdx.x >> 5, h = blockIdx.x & 31;
  int tid = threadIdx.x;
  __shared__ float Ms[64][65];
  __shared__ float Cs[64][65];
  __shared__ float xss[64][36];
  __shared__ float Hss[64][36];
  __shared__ float lcds[64], dts[64];
  int t0 = c * CHUNK;
  int t = tid >> 2, q = tid & 3;
  const float* row = xBC + (size_t)(t0 + t) * CONVCH;
#pragma unroll
  for (int j = 0; j < 16; j += 4) {
    float4 cv = *(const float4*)(row + DINNER + 64 + q * 16 + j);
    Cs[t][q * 16 + j + 0] = cv.x; Cs[t][q * 16 + j + 1] = cv.y;
    Cs[t][q * 16 + j + 2] = cv.z; Cs[t][q * 16 + j + 3] = cv.w;
  }
  if (q < 2) {
#pragma unroll
    for (int j = 0; j < 16; j += 4)
      *(float4*)&xss[t][q * 16 + j] = *(const float4*)(row + h * 32 + q * 16 + j);
  }
  {
    const float* gp = G + ((size_t)c * 64 + t) * 64 + q * 16;
#pragma unroll
    for (int j = 0; j < 16; j += 4) {
      float4 g = *(const float4*)(gp + j);
      Ms[t][q * 16 + j + 0] = g.x; Ms[t][q * 16 + j + 1] = g.y;
      Ms[t][q * 16 + j + 2] = g.z; Ms[t][q * 16 + j + 3] = g.w;
    }
  }
  {
    const float* hp = hstate + ((size_t)c * 32 + h) * 2048 + tid * 8;
    int n = tid >> 2, p0 = (tid & 3) * 8;
    *(float4*)&Hss[n][p0]     = *(const float4*)hp;
    *(float4*)&Hss[n][p0 + 4] = *(const float4*)(hp + 4);
  }
  if (tid < 64) {
    lcds[tid] = lcd[((size_t)c * 32 + h) * CHUNK + tid];
    dts[tid]  = dt[(t0 + tid) * MNH + h];
  }
  __syncthreads();
  {
    int s0 = q * 16;
#pragma unroll
    for (int j = 0; j < 16; ++j) {
      int s = s0 + j;
      float m = (s <= t) ? expf(lcds[t] - lcds[s]) * dts[s] * Ms[t][s] : 0.f;
      Ms[t][s] = m;
    }
  }
  __syncthreads();
  int pg = q * 8;
  f32x4 y0 = {}, y1 = {}, a0 = {}, a1 = {};
  for (int s = 0; s < 64; ++s) {
    f32x4 m = splat4(Ms[t][s]);
    y0 += m * *(const f32x4*)&xss[s][pg];
    y1 += m * *(const f32x4*)&xss[s][pg + 4];
  }
  for (int n = 0; n < 64; ++n) {
    f32x4 cn = splat4(Cs[t][n]);
    a0 += cn * *(const f32x4*)&Hss[n][pg];
    a1 += cn * *(const f32x4*)&Hss[n][pg + 4];
  }
  f32x4 cd = splat4(expf(lcds[t]));
  y0 += cd * a0; y1 += cd * a1;
  float* yp = y + (size_t)(t0 + t) * DINNER + h * 32 + pg;
  *(f32x4*)yp = y0; *(f32x4*)(yp + 4) = y1;
}

// ---------------- gate + RMSNorm ----------------
__global__ __launch_bounds__(256) void gatenorm_kernel(
    const float* __restrict__ y_ssm, const float* __restrict__ xBC,
    const float* __restrict__ zxbcdt, const float* __restrict__ Dv,
    const float* __restrict__ norm_w, float* __restrict__ out) {
  int l = blockIdx.x, tid = threadIdx.x;
  float vals[4];
  float ss = 0.f;
#pragma unroll
  for (int i = 0; i < 4; ++i) {
    int d = tid + i * 256;
    int h = d >> 5;
    float v = y_ssm[(size_t)l * DINNER + d] + Dv[h] * xBC[(size_t)l * CONVCH + d];
    float z = zxbcdt[(size_t)l * INDIMP + d];
    v *= z / (1.f + expf(-z));
    vals[i] = v;
    ss += v * v;
  }
#pragma unroll
  for (int off = 32; off > 0; off >>= 1) ss += __shfl_xor(ss, off);
  __shared__ float sred[4];
  if ((tid & 63) == 0) sred[tid >> 6] = ss;
  __syncthreads();
  float tot = sred[0] + sred[1] + sred[2] + sred[3];
  float scale = rsqrtf(tot * (1.f / 1024.f) + 1e-5f);
#pragma unroll
  for (int i = 0; i < 4; ++i) {
    int d = tid + i * 256;
    out[(size_t)l * DINNER + d] = vals[i] * scale * norm_w[d];
  }
}

// ---------------- per-row top-64 radix select ----------------
__global__ __launch_bounds__(256) void topk_kernel(
    const float* __restrict__ scores, int* __restrict__ out_idx) {
  int l = blockIdx.x, tid = threadIdx.x;
  if (l < 64) {
    if (tid < 64) out_idx[l * 64 + tid] = tid;
    return;
  }
  int n = l + 1;
  const float* row = scores + (size_t)l * L;
  __shared__ int hist[256];
  __shared__ unsigned sel_prefix;
  __shared__ int sel_remaining;
  __shared__ int cnt_g, cnt_e;
  __shared__ int eq_list[128];
  if (tid == 0) { cnt_g = 0; cnt_e = 0; }
  unsigned prefix = 0;
  int remaining = 64;
  for (int pass = 0; pass < 4; ++pass) {
    int shift = 24 - 8 * pass;
    unsigned himask = (pass == 0) ? 0u : (0xFFFFFFFFu << (shift + 8));
    hist[tid] = 0;
    __syncthreads();
    for (int j = tid; j < n; j += 256) {
      unsigned u = __float_as_uint(row[j]);
      unsigned key = (u & 0x80000000u) ? ~u : (u | 0x80000000u);
      if (((key ^ prefix) & himask) == 0)
        atomicAdd(&hist[(key >> shift) & 255], 1);
    }
    __syncthreads();
    if (tid == 0) {
      int cum = 0, b = 255;
      for (; b >= 0; --b) {
        cum += hist[b];
        if (cum >= remaining) break;
      }
      sel_prefix = prefix | ((unsigned)b << shift);
      sel_remaining = remaining - (cum - hist[b]);
    }
    __syncthreads();
    prefix = sel_prefix;
    remaining = sel_remaining;
    __syncthreads();
  }
  unsigned T = prefix;
  for (int j = tid; j < n; j += 256) {
    unsigned u = __float_as_uint(row[j]);
    unsigned key = (u & 0x80000000u) ? ~u : (u | 0x80000000u);
    if (key > T) {
      int p = atomicAdd(&cnt_g, 1);
      out_idx[l * 64 + p] = j;
    } else if (key == T) {
      int p = atomicAdd(&cnt_e, 1);
      if (p < 128) eq_list[p] = j;
    }
  }
  __syncthreads();
  if (tid == 0) {
    int G = cnt_g;
    int E = remaining;
    int m = cnt_e < 128 ? cnt_e : 128;
    for (int e = 0; e < E; ++e) {
      int best = 0, bj = 0x7fffffff;
      for (int i = 0; i < m; ++i)
        if (eq_list[i] < bj) { bj = eq_list[i]; best = i; }
      out_idx[l * 64 + G + e] = bj;
      eq_list[best] = 0x7fffffff;
    }
  }
}

// ---------------- RoPE + pack q_final/k_final (fused-buffer strides) ----------------
__global__ __launch_bounds__(128) void rope_pack_kernel(
    const float* __restrict__ qbuf, const float* __restrict__ kv,
    const float* __restrict__ c3,
    float* __restrict__ q_final, float* __restrict__ k_final) {
  int l = blockIdx.x, tid = threadIdx.x;
  __shared__ float s_s[16], s_c[16];
  if (tid < 16) {
    float inv = powf(10000.f, -(float)tid / 16.f);
    float ang = (float)l * inv;
    s_s[tid] = sinf(ang);
    s_c[tid] = cosf(ang);
  }
  __syncthreads();
  const float* qrow = qbuf + (size_t)l * 1536;
  const float* krow = c3 + (size_t)l * 384 + 256;
  for (int e = tid; e < NH * 96; e += 128) {
    int hh = e / 96, d = e - hh * 96;
    float qv, kvv;
    if (d < 64) {
      qv  = qrow[hh * 64 + d];
      kvv = kv[(size_t)l * 2048 + hh * 64 + d];
    } else {
      int r = d - 64;
      if (r < 16) {
        float q1 = qrow[1024 + hh * 32 + r];
        float q2 = qrow[1024 + hh * 32 + 16 + r];
        qv = q1 * s_c[r] - q2 * s_s[r];
        float k1 = krow[r];
        float k2 = krow[16 + r];
        kvv = k1 * s_c[r] - k2 * s_s[r];
      } else {
        int rr = r - 16;
        float q1 = qrow[1024 + hh * 32 + rr];
        float q2 = qrow[1024 + hh * 32 + 16 + rr];
        qv = q1 * s_s[rr] + q2 * s_c[rr];
        float k1 = krow[rr];
        float k2 = krow[16 + rr];
        kvv = k1 * s_s[rr] + k2 * s_c[rr];
      }
    }
    q_final[(size_t)l * 1536 + e] = qv;
    k_final[(size_t)l * 1536 + e] = kvv;
  }
}

// ---------------- sparse attention ----------------
__global__ __launch_bounds__(256) void attn_kernel(
    const float* __restrict__ q_final, const float* __restrict__ k_final,
    const float* __restrict__ kv, const int* __restrict__ idx,
    unsigned short* __restrict__ attn_aug) {
  int w = blockIdx.x * 4 + (threadIdx.x >> 6);
  int lane = threadIdx.x & 63;
  int l = w >> 4, h = w & 15;
  int ik = idx[l * 64 + lane];
  const float4* qp = (const float4*)(q_final + (size_t)l * 1536 + h * 96);
  const float4* kp = (const float4*)(k_final + (size_t)ik * 1536 + h * 96);
  float dot = 0.f;
#pragma unroll
  for (int j = 0; j < 24; ++j) {
    float4 q4 = qp[j], k4 = kp[j];
    dot += q4.x * k4.x + q4.y * k4.y + q4.z * k4.z + q4.w * k4.w;
  }
  float logit = dot * 0.10206207261596575f;
  float m = logit;
#pragma unroll
  for (int off = 32; off > 0; off >>= 1) m = fmaxf(m, __shfl_xor(m, off));
  float e = expf(logit - m);
  float ssum = e;
#pragma unroll
  for (int off = 32; off > 0; off >>= 1) ssum += __shfl_xor(ssum, off);
  float wgt = e / ssum;
  float acc = 0.f;
  const float* vbase = kv + 1024 + h * 64 + lane;
  for (int k = 0; k < 64; ++k) {
    float wk = __shfl(wgt, k);
    int kk = __shfl(ik, k);
    acc += wk * vbase[(size_t)kk * 2048];
  }
  unsigned short hi = f2bf(acc);
  unsigned short lo = f2bf(acc - bf2f(hi));
  size_t o = ((size_t)l * 1024 + h * 64 + lane) * 3;
  attn_aug[o] = hi; attn_aug[o + 1] = lo; attn_aug[o + 2] = hi;
}

// ---------------- host ----------------
extern "C" void kernel_launch(void* const* d_in, const int* in_sizes, int n_in,
                              void* d_out, int out_size, void* d_ws, size_t ws_size,
                              hipStream_t stream) {
  const float* x          = (const float*)d_in[0];
  const float* idx_in_w   = (const float*)d_in[1];
  const float* idx_conv_w = (const float*)d_in[2];
  const float* idx_conv_b = (const float*)d_in[3];
  const float* idx_dt_b   = (const float*)d_in[4];
  const float* idx_A_log  = (const float*)d_in[5];
  const float* idx_D      = (const float*)d_in[6];
  const float* idx_norm_w = (const float*)d_in[7];
  const float* idx_out_w  = (const float*)d_in[8];
  const float* idx_q_w    = (const float*)d_in[9];
  const float* idx_k_w    = (const float*)d_in[10];
  const float* q_down_w   = (const float*)d_in[11];
  const float* q_up_w     = (const float*)d_in[12];
  const float* q_rope_w   = (const float*)d_in[13];
  const float* kv_down_w  = (const float*)d_in[14];
  const float* kv_up_w    = (const float*)d_in[15];
  const float* k_rope_w   = (const float*)d_in[16];
  const float* out_w      = (const float*)d_in[17];
  float* out = (float*)d_out;

  // ---- workspace arena (float slots); R12 bug: trip buffers were half-sized.
  // x_trip = 2048*6144 ush = 6,291,456 fl; w_in_trip = 2304*6144 ush = 7,077,888 fl.
  float* p = (float*)d_ws;
  float* segA = p; p += 4718592;  // zxbcdt[2048x2304] | scores | qbuf
  float* segB = p; p += 2359296;  // xBC | {q_idx, k_idx, c3}
  float* dtb = p; p += 65536;
  float* logdA = p; p += 65536;
  float* lcdb = p; p += 65536;
  int*   idxb = (int*)p; p += 131072;
  float* segD = p; p += 4194304;  // y_ssm+hstate | kvb
  float* segBig1 = p; p += 6291456;  // x_trip | w_outp_aug (after in_proj)
  float* segBig2 = p; p += 7077888;  // w_in_trip | {y_norm|x_aug|q_final}@0, attn_aug@3145728
  float* segH = p; p += 3145728;     // {out_w_T,qwpad,Wq} | k_final
  unsigned short* w_3down_aug = (unsigned short*)p; p += 589824;
  unsigned short* w_qups_aug  = (unsigned short*)p; p += 294912;
  unsigned short* w_kvup_aug  = (unsigned short*)p; p += 393216;
  unsigned short* c_q_aug     = (unsigned short*)p; p += 393216;
  unsigned short* c_kv_aug    = (unsigned short*)p; p += 393216;
  float* Gbuf = p; p += 131072;
  // total ~30.3M floats ~121 MB

  float* zxbcdt = segA;
  float* scores = segA;
  float* qbuf   = segA;
  float* xBC    = segB;
  float* q_idx  = segB;
  float* k_idx  = segB + 131072;
  float* c3     = segB + 262144;
  float* y_ssm  = segD;
  float* hstate = segD + 2097152;
  float* kvb    = segD;
  unsigned short* x_trip     = (unsigned short*)segBig1;  // dead after in_proj
  unsigned short* w_outp_aug = (unsigned short*)segBig1;  // written after in_proj
  unsigned short* w_in_trip  = (unsigned short*)segBig2;  // dead after in_proj
  float* y_norm  = segBig2;                               // gatenorm..q_idx gemm
  unsigned short* x_aug = (unsigned short*)segBig2;       // after topk..down-proj
  float* q_final = segBig2;                               // rope_pack..attn
  unsigned short* attn_aug = (unsigned short*)(segBig2 + 3145728);
  float* out_w_T = segH;
  float* qwpad   = segH + 1048576;
  float* Wq      = segH + 1179648;
  float* k_final = segH;                                  // after q_idx gemm

  dim3 blk(256);
  auto cdiv = [](int a, int b) { return (a + b - 1) / b; };
  auto gemmf3 = [&](const float* A, const float* W, float* C, int M, int N, int K, int S) {
    dim3 grid(cdiv(N, 128), M / 128, S);
    hipLaunchKernelGGL(gemm_f32_v3, grid, blk, 0, stream, A, W, C, M, N, K);
  };
  auto gemmb = [&](const unsigned short* A, const unsigned short* W, float* C,
                   int M, int N, int K, int lda, int ldb, int ldc, int S) {
    dim3 grid(N / 128, M / 128, S);
    hipLaunchKernelGGL(gemm_bf16_kernel, grid, blk, 0, stream, A, W, C, M, N, K, lda, ldb, ldc);
  };
  auto caugA = [&](const float* s, unsigned short* d, int total, int K, int sld) {
    hipLaunchKernelGGL(conv_augA_kernel, dim3(cdiv(total, 256)), blk, 0, stream, s, d, total, K, sld);
  };
  auto caugW = [&](const float* s, unsigned short* d, int rows, int total, int K, int sld) {
    hipLaunchKernelGGL(conv_augW_kernel, dim3(cdiv(total, 256)), blk, 0, stream, s, d, rows, total, K, sld);
  };

  // ---- weight precomputes ----
  hipLaunchKernelGGL(transpose1024_kernel, dim3(1024), blk, 0, stream, idx_out_w, out_w_T);
  hipMemsetAsync(qwpad, 0, 131072 * 4, stream);
  hipMemcpyAsync(qwpad, idx_q_w, (size_t)64 * 1024 * 4, hipMemcpyDeviceToDevice, stream);
  hipMemsetAsync(Wq, 0, 131072 * 4, stream);
  gemmf3(qwpad, out_w_T, Wq, 128, 1024, 1024, 8);
  hipLaunchKernelGGL(conv_tripA_kernel, dim3(cdiv(2048 * 1024, 256)), blk, 0, stream,
                     x, x_trip, 2048 * 1024, 1024);
  hipLaunchKernelGGL(conv_tripW_kernel, dim3(cdiv(2304 * 1024, 256)), blk, 0, stream,
                     idx_in_w, w_in_trip, 2208, 2304 * 1024, 1024);
  caugW(q_down_w,  w_3down_aug,                    128, 128 * 1024, 1024, 1024);
  caugW(kv_down_w, w_3down_aug + 128 * 1024 * 3,   128, 128 * 1024, 1024, 1024);
  caugW(k_rope_w,  w_3down_aug + 256 * 1024 * 3,    32, 128 * 1024, 1024, 1024);
  caugW(q_up_w,    w_qups_aug,                    1024, 1024 * 128, 128, 128);
  caugW(q_rope_w,  w_qups_aug + 1024 * 128 * 3,    512, 512 * 128, 128, 128);
  caugW(kv_up_w,   w_kvup_aug, 2048, 2048 * 128, 128, 128);

  // ---- mamba branch: in_proj via triple-split MFMA (fp32-accurate) ----
  hipMemsetAsync(zxbcdt, 0, (size_t)L * INDIMP * 4, stream);
  gemmb(x_trip, w_in_trip, zxbcdt, 2048, 2304, 6144, 6144, 6144, INDIMP, 2);
  // x_trip dead -> write out-proj weights into segBig1
  caugW(out_w, w_outp_aug, 1024, 1024 * 1024, 1024, 1024);
  hipLaunchKernelGGL(conv_silu_kernel, dim3(cdiv(L * CONVCH, 256)), blk, 0, stream,
                     zxbcdt, idx_conv_w, idx_conv_b, xBC);
  hipLaunchKernelGGL(dt_kernel, dim3(L * MNH / 256), blk, 0, stream,
                     zxbcdt, idx_dt_b, idx_A_log, dtb, logdA);
  hipLaunchKernelGGL(lcd_kernel, dim3(4), blk, 0, stream, logdA, lcdb);
  hipLaunchKernelGGL(chunk_G_kernel, dim3(NCH), blk, 0, stream, xBC, Gbuf);
  hipLaunchKernelGGL(scan_local_kernel, dim3(NCH * MNH), blk, 0, stream,
                     xBC, dtb, lcdb, hstate);
  hipLaunchKernelGGL(scan_combine_kernel, dim3(256), blk, 0, stream, hstate, lcdb);
  hipLaunchKernelGGL(scan_y_kernel, dim3(NCH * MNH), blk, 0, stream,
                     xBC, Gbuf, dtb, lcdb, hstate, y_ssm);
  // y_norm -> segBig2 (w_in_trip dead)
  hipLaunchKernelGGL(gatenorm_kernel, dim3(L), blk, 0, stream,
                     y_ssm, xBC, zxbcdt, idx_D, idx_norm_w, y_norm);

  // ---- index scores + topk (out-proj folded into Wq) ----
  hipMemsetAsync(q_idx, 0, 131072 * 4, stream);
  hipMemsetAsync(k_idx, 0, 131072 * 4, stream);
  gemmf3(y_norm, Wq, q_idx, 2048, 64, 1024, 16);
  gemmf3(x, idx_k_w, k_idx, 2048, 64, 1024, 16);
  gemmf3(q_idx, k_idx, scores, 2048, 2048, 64, 1);
  hipLaunchKernelGGL(topk_kernel, dim3(L), blk, 0, stream, scores, idxb);

  // ---- attention value path (aug split-bf16 MFMA) ----
  caugA(x, x_aug, 2048 * 1024, 1024, 1024);  // segBig2@0 (y_norm dead)
  hipMemsetAsync(c3, 0, 786432 * 4, stream);
  gemmb(x_aug, w_3down_aug, c3, 2048, 384, 3072, 3072, 3072, 384, 8);
  caugA(c3, c_q_aug, 2048 * 128, 128, 384);
  caugA(c3 + 128, c_kv_aug, 2048 * 128, 128, 384);
  gemmb(c_q_aug, w_qups_aug, qbuf, 2048, 1536, 384, 384, 384, 1536, 1);
  gemmb(c_kv_aug, w_kvup_aug, kvb, 2048, 2048, 384, 384, 384, 2048, 1);
  hipLaunchKernelGGL(rope_pack_kernel, dim3(L), dim3(128), 0, stream,
                     qbuf, kvb, c3, q_final, k_final);

  // ---- sparse attention + output projection ----
  hipLaunchKernelGGL(attn_kernel, dim3(L * NH / 4), blk, 0, stream,
                     q_final, k_final, kvb, idxb, attn_aug);
  hipMemsetAsync(out, 0, (size_t)out_size * 4, stream);
  gemmb(attn_aug, w_outp_aug, out, 2048, 1024, 3072, 3072, 3072, 1024, 2);
}